// Round 1
// baseline (1744.261 us; speedup 1.0000x reference)
//
#include <hip/hip_runtime.h>

#define N_NODES   100000
#define N_EDGES   1600000
#define N_FEAT    128
#define HIDDEN    128
#define N_CLASSES 64

// ---------------------------------------------------------------------------
// Edge-index width detector: reference says int64 but harness doc says int32.
// For int64 data (values < 2^17, non-negative) every odd 32-bit word is 0.
// For int32 data, odd words are random node indices (P(all 1024 == 0) ~ 0).
// flag = 1 -> int64 layout, 0 -> int32 layout. Device-side, graph-safe.
// ---------------------------------------------------------------------------
__global__ void detect_kernel(const int* __restrict__ e32, int* __restrict__ flag) {
    __shared__ int nz;
    if (threadIdx.x == 0) nz = 0;
    __syncthreads();
    int v = 0;
    for (int i = threadIdx.x; i < 1024; i += 256) v |= e32[2 * i + 1];
    if (v) atomicOr(&nz, 1);
    __syncthreads();
    if (threadIdx.x == 0) *flag = (nz == 0) ? 1 : 0;
}

__device__ __forceinline__ int load_src(const int* e, int is64, int i) {
    return is64 ? e[2 * i] : e[i];
}
__device__ __forceinline__ int load_dst(const int* e, int is64, int i) {
    return is64 ? e[2 * (N_EDGES + i)] : e[N_EDGES + i];
}

__global__ void deg_kernel(const int* __restrict__ e, const int* __restrict__ flag,
                           float* __restrict__ deg) {
    int i = blockIdx.x * blockDim.x + threadIdx.x;
    if (i >= N_EDGES) return;
    int is64 = *flag;
    atomicAdd(&deg[load_dst(e, is64, i)], 1.0f);
}

__global__ void inv_deg_kernel(float* __restrict__ deg) {
    int i = blockIdx.x * blockDim.x + threadIdx.x;
    if (i < N_NODES) deg[i] = 1.0f / fmaxf(deg[i], 1.0f);
}

// One thread per (edge, feature). feat has 128 cols for both layers.
__global__ void scatter_kernel(const int* __restrict__ e, const int* __restrict__ flag,
                               const float* __restrict__ feat, float* __restrict__ agg) {
    int i = blockIdx.x * blockDim.x + threadIdx.x;   // < 204.8M, fits int32
    int edge = i >> 7;
    int f = i & 127;
    if (edge >= N_EDGES) return;
    int is64 = *flag;
    int s = load_src(e, is64, edge);
    int d = load_dst(e, is64, edge);
    atomicAdd(&agg[(size_t)d * 128 + f], feat[(size_t)s * 128 + f]);
}

// h = relu(inv_deg[r]*agg[r] @ W_l + x[r] @ W_r + b), 128 outputs/row.
// 128 threads = 128 output cols, 8 rows per block staged in LDS.
__global__ void __launch_bounds__(128) gemm1_kernel(
        const float* __restrict__ agg, const float* __restrict__ x,
        const float* __restrict__ inv_deg,
        const float* __restrict__ W_l, const float* __restrict__ W_r,
        const float* __restrict__ b, float* __restrict__ h) {
    __shared__ float s_a[8][128];
    __shared__ float s_x[8][128];
    const int f = threadIdx.x;
    const int r0 = blockIdx.x * 8;
    #pragma unroll
    for (int r = 0; r < 8; r++) {
        float id = inv_deg[r0 + r];
        s_a[r][f] = agg[(size_t)(r0 + r) * 128 + f] * id;
        s_x[r][f] = x[(size_t)(r0 + r) * 128 + f];
    }
    __syncthreads();
    float acc[8];
    const float bf = b[f];
    #pragma unroll
    for (int r = 0; r < 8; r++) acc[r] = bf;
    for (int k4 = 0; k4 < 32; k4++) {
        float4 a4[8], x4[8];
        #pragma unroll
        for (int r = 0; r < 8; r++) {
            a4[r] = *(const float4*)&s_a[r][k4 * 4];
            x4[r] = *(const float4*)&s_x[r][k4 * 4];
        }
        #pragma unroll
        for (int j = 0; j < 4; j++) {
            float wl = W_l[(k4 * 4 + j) * 128 + f];
            float wr = W_r[(k4 * 4 + j) * 128 + f];
            #pragma unroll
            for (int r = 0; r < 8; r++) {
                float av = (j == 0) ? a4[r].x : (j == 1) ? a4[r].y : (j == 2) ? a4[r].z : a4[r].w;
                float xv = (j == 0) ? x4[r].x : (j == 1) ? x4[r].y : (j == 2) ? x4[r].z : x4[r].w;
                acc[r] = fmaf(av, wl, acc[r]);
                acc[r] = fmaf(xv, wr, acc[r]);
            }
        }
    }
    #pragma unroll
    for (int r = 0; r < 8; r++)
        h[(size_t)(r0 + r) * 128 + f] = fmaxf(acc[r], 0.0f);
}

// out = inv_deg[r]*agg[r] @ W2_l + h[r] @ W2_r + b2, 64 outputs/row, no relu.
__global__ void __launch_bounds__(64) gemm2_kernel(
        const float* __restrict__ agg, const float* __restrict__ h,
        const float* __restrict__ inv_deg,
        const float* __restrict__ W_l, const float* __restrict__ W_r,
        const float* __restrict__ b, float* __restrict__ out) {
    __shared__ float s_a[8][128];
    __shared__ float s_h[8][128];
    const int f = threadIdx.x;           // 0..63
    const int r0 = blockIdx.x * 8;
    #pragma unroll
    for (int r = 0; r < 8; r++) {
        float id = inv_deg[r0 + r];
        for (int c = f; c < 128; c += 64) {
            s_a[r][c] = agg[(size_t)(r0 + r) * 128 + c] * id;
            s_h[r][c] = h[(size_t)(r0 + r) * 128 + c];
        }
    }
    __syncthreads();
    float acc[8];
    const float bf = b[f];
    #pragma unroll
    for (int r = 0; r < 8; r++) acc[r] = bf;
    for (int k4 = 0; k4 < 32; k4++) {
        float4 a4[8], h4[8];
        #pragma unroll
        for (int r = 0; r < 8; r++) {
            a4[r] = *(const float4*)&s_a[r][k4 * 4];
            h4[r] = *(const float4*)&s_h[r][k4 * 4];
        }
        #pragma unroll
        for (int j = 0; j < 4; j++) {
            float wl = W_l[(k4 * 4 + j) * 64 + f];
            float wr = W_r[(k4 * 4 + j) * 64 + f];
            #pragma unroll
            for (int r = 0; r < 8; r++) {
                float av = (j == 0) ? a4[r].x : (j == 1) ? a4[r].y : (j == 2) ? a4[r].z : a4[r].w;
                float hv = (j == 0) ? h4[r].x : (j == 1) ? h4[r].y : (j == 2) ? h4[r].z : h4[r].w;
                acc[r] = fmaf(av, wl, acc[r]);
                acc[r] = fmaf(hv, wr, acc[r]);
            }
        }
    }
    #pragma unroll
    for (int r = 0; r < 8; r++)
        out[(size_t)(r0 + r) * 64 + f] = acc[r];
}

extern "C" void kernel_launch(void* const* d_in, const int* in_sizes, int n_in,
                              void* d_out, int out_size, void* d_ws, size_t ws_size,
                              hipStream_t stream) {
    const float* x    = (const float*)d_in[0];
    const int*   edge = (const int*)d_in[1];
    const float* W1_l = (const float*)d_in[2];
    const float* b1   = (const float*)d_in[3];
    const float* W1_r = (const float*)d_in[4];
    const float* W2_l = (const float*)d_in[5];
    const float* b2   = (const float*)d_in[6];
    const float* W2_r = (const float*)d_in[7];
    float* out = (float*)d_out;
    float* ws  = (float*)d_ws;

    // workspace layout (floats): [deg 131072][agg 12.8M][h 12.8M][flag]
    float* deg  = ws;
    float* agg  = ws + 131072;
    float* h    = agg + 12800000;
    int*   flag = (int*)(h + 12800000);

    detect_kernel<<<1, 256, 0, stream>>>(edge, flag);
    hipMemsetAsync(deg, 0, (size_t)(131072 + 12800000) * 4, stream);

    deg_kernel<<<(N_EDGES + 255) / 256, 256, 0, stream>>>(edge, flag, deg);
    inv_deg_kernel<<<(N_NODES + 255) / 256, 256, 0, stream>>>(deg);

    // layer 1
    scatter_kernel<<<800000, 256, 0, stream>>>(edge, flag, x, agg);
    gemm1_kernel<<<12500, 128, 0, stream>>>(agg, x, deg, W1_l, W1_r, b1, h);

    // layer 2
    hipMemsetAsync(agg, 0, (size_t)12800000 * 4, stream);
    scatter_kernel<<<800000, 256, 0, stream>>>(edge, flag, h, agg);
    gemm2_kernel<<<12500, 64, 0, stream>>>(agg, h, deg, W2_l, W2_r, b2, out);
}

// Round 2
// 668.020 us; speedup vs baseline: 2.6111x; 2.6111x over previous
//
#include <hip/hip_runtime.h>

#define N_NODES   100000
#define N_EDGES   1600000
#define N_FEAT    128
#define HIDDEN    128
#define N_CLASSES 64

// ---------------------------------------------------------------------------
// Edge-index width detector (int64 vs int32 layout), device-side, graph-safe.
// ---------------------------------------------------------------------------
__global__ void detect_kernel(const int* __restrict__ e32, int* __restrict__ flag) {
    __shared__ int nz;
    if (threadIdx.x == 0) nz = 0;
    __syncthreads();
    int v = 0;
    for (int i = threadIdx.x; i < 1024; i += 256) v |= e32[2 * i + 1];
    if (v) atomicOr(&nz, 1);
    __syncthreads();
    if (threadIdx.x == 0) *flag = (nz == 0) ? 1 : 0;
}

__device__ __forceinline__ int load_src(const int* e, int is64, int i) {
    return is64 ? e[2 * i] : e[i];
}
__device__ __forceinline__ int load_dst(const int* e, int is64, int i) {
    return is64 ? e[2 * (N_EDGES + i)] : e[N_EDGES + i];
}

// -------------------- CSR construction --------------------
__global__ void deg_count_kernel(const int* __restrict__ e, const int* __restrict__ flag,
                                 int* __restrict__ deg_i) {
    int i = blockIdx.x * blockDim.x + threadIdx.x;
    if (i >= N_EDGES) return;
    int is64 = *flag;
    atomicAdd(&deg_i[load_dst(e, is64, i)], 1);
}

// scan phase 1: 98 blocks x 256 thr x 4 elems -> per-element exclusive-in-block
__global__ __launch_bounds__(256) void scan1_kernel(const int* __restrict__ deg_i,
                                                    int* __restrict__ pre,
                                                    int* __restrict__ blk) {
    __shared__ int s[256];
    int base = blockIdx.x * 1024 + threadIdx.x * 4;
    int v0 = 0, v1 = 0, v2 = 0, v3 = 0;
    if (base + 3 < N_NODES) {
        int4 q = *(const int4*)&deg_i[base];
        v0 = q.x; v1 = q.y; v2 = q.z; v3 = q.w;
    } else {
        if (base + 0 < N_NODES) v0 = deg_i[base + 0];
        if (base + 1 < N_NODES) v1 = deg_i[base + 1];
        if (base + 2 < N_NODES) v2 = deg_i[base + 2];
        if (base + 3 < N_NODES) v3 = deg_i[base + 3];
    }
    int tsum = v0 + v1 + v2 + v3;
    s[threadIdx.x] = tsum;
    __syncthreads();
    for (int off = 1; off < 256; off <<= 1) {
        int t = (threadIdx.x >= off) ? s[threadIdx.x - off] : 0;
        __syncthreads();
        s[threadIdx.x] += t;
        __syncthreads();
    }
    int excl = s[threadIdx.x] - tsum;   // exclusive prefix of this thread in block
    pre[base + 0] = excl;
    pre[base + 1] = excl + v0;
    pre[base + 2] = excl + v0 + v1;
    pre[base + 3] = excl + v0 + v1 + v2;
    if (threadIdx.x == 255) blk[blockIdx.x] = s[255];
}

// scan phase 2: single block scans 98 block totals -> exclusive block offsets
__global__ __launch_bounds__(128) void scan2_kernel(int* __restrict__ blk) {
    __shared__ int s[128];
    int v = (threadIdx.x < 98) ? blk[threadIdx.x] : 0;
    s[threadIdx.x] = v;
    __syncthreads();
    for (int off = 1; off < 128; off <<= 1) {
        int t = (threadIdx.x >= off) ? s[threadIdx.x - off] : 0;
        __syncthreads();
        s[threadIdx.x] += t;
        __syncthreads();
    }
    if (threadIdx.x < 98) blk[threadIdx.x] = s[threadIdx.x] - v;
}

// scan phase 3: finalize cursor (=row start) and inv_deg
__global__ __launch_bounds__(256) void scan3_kernel(const int* __restrict__ pre,
                                                    const int* __restrict__ blk,
                                                    const int* __restrict__ deg_i,
                                                    int* __restrict__ cursor,
                                                    float* __restrict__ inv_deg) {
    int off = blk[blockIdx.x];
    int base = blockIdx.x * 1024 + threadIdx.x * 4;
    #pragma unroll
    for (int j = 0; j < 4; j++) {
        int idx = base + j;
        if (idx < N_NODES) {
            cursor[idx] = pre[idx] + off;
            inv_deg[idx] = 1.0f / fmaxf((float)deg_i[idx], 1.0f);
        }
    }
}

__global__ void fill_kernel(const int* __restrict__ e, const int* __restrict__ flag,
                            int* __restrict__ cursor, int* __restrict__ col) {
    int i = blockIdx.x * blockDim.x + threadIdx.x;
    if (i >= N_EDGES) return;
    int is64 = *flag;
    int s = load_src(e, is64, i);
    int d = load_dst(e, is64, i);
    int pos = atomicAdd(&cursor[d], 1);
    col[pos] = s;
}

// -------------------- gather aggregation --------------------
// 128-col features: 32 lanes/node, float4 each. 8 nodes per 256-block.
// After fill, cursor[n] = row_start + deg -> start = cursor[n] - deg.
__global__ __launch_bounds__(256) void agg128_kernel(
        const int* __restrict__ cursor, const int* __restrict__ deg_i,
        const int* __restrict__ col, const float* __restrict__ feat,
        const float* __restrict__ inv_deg, float* __restrict__ agg) {
    int node = blockIdx.x * 8 + (threadIdx.x >> 5);
    int lane = threadIdx.x & 31;
    int cnt = deg_i[node];
    int start = cursor[node] - cnt;
    float4 acc = {0.f, 0.f, 0.f, 0.f};
    int s = (cnt > 0) ? col[start] : 0;
    for (int k = 0; k < cnt; k++) {
        int snext = (k + 1 < cnt) ? col[start + k + 1] : 0;
        float4 v = ((const float4*)(feat + (size_t)s * 128))[lane];
        acc.x += v.x; acc.y += v.y; acc.z += v.z; acc.w += v.w;
        s = snext;
    }
    float sc = inv_deg[node];
    acc.x *= sc; acc.y *= sc; acc.z *= sc; acc.w *= sc;
    ((float4*)(agg + (size_t)node * 128))[lane] = acc;
}

// 64-col features: 16 lanes/node, float4 each. 16 nodes per 256-block.
__global__ __launch_bounds__(256) void agg64_kernel(
        const int* __restrict__ cursor, const int* __restrict__ deg_i,
        const int* __restrict__ col, const float* __restrict__ feat,
        const float* __restrict__ inv_deg, float* __restrict__ agg) {
    int node = blockIdx.x * 16 + (threadIdx.x >> 4);
    int lane = threadIdx.x & 15;
    int cnt = deg_i[node];
    int start = cursor[node] - cnt;
    float4 acc = {0.f, 0.f, 0.f, 0.f};
    int s = (cnt > 0) ? col[start] : 0;
    for (int k = 0; k < cnt; k++) {
        int snext = (k + 1 < cnt) ? col[start + k + 1] : 0;
        float4 v = ((const float4*)(feat + (size_t)s * 64))[lane];
        acc.x += v.x; acc.y += v.y; acc.z += v.z; acc.w += v.w;
        s = snext;
    }
    float sc = inv_deg[node];
    acc.x *= sc; acc.y *= sc; acc.z *= sc; acc.w *= sc;
    ((float4*)(agg + (size_t)node * 64))[lane] = acc;
}

// -------------------- GEMMs --------------------
// h = relu(agg1 @ W1_l + x @ W1_r + b1); agg1 already scaled by inv_deg.
__global__ void __launch_bounds__(128) gemm1_kernel(
        const float* __restrict__ agg, const float* __restrict__ x,
        const float* __restrict__ W_l, const float* __restrict__ W_r,
        const float* __restrict__ b, float* __restrict__ h) {
    __shared__ float s_a[8 * 128];
    __shared__ float s_x[8 * 128];
    const int f = threadIdx.x;
    const int r0 = blockIdx.x * 8;
    {   // vector staging: 1024 floats each = 256 float4 / 128 threads
        const float4* av = (const float4*)(agg + (size_t)r0 * 128);
        const float4* xv = (const float4*)(x + (size_t)r0 * 128);
        float4* sa = (float4*)s_a;
        float4* sx = (float4*)s_x;
        for (int t = f; t < 256; t += 128) { sa[t] = av[t]; sx[t] = xv[t]; }
    }
    __syncthreads();
    float acc[8];
    const float bf = b[f];
    #pragma unroll
    for (int r = 0; r < 8; r++) acc[r] = bf;
    for (int k4 = 0; k4 < 32; k4++) {
        float4 a4[8], x4[8];
        #pragma unroll
        for (int r = 0; r < 8; r++) {
            a4[r] = *(const float4*)&s_a[r * 128 + k4 * 4];
            x4[r] = *(const float4*)&s_x[r * 128 + k4 * 4];
        }
        #pragma unroll
        for (int j = 0; j < 4; j++) {
            float wl = W_l[(k4 * 4 + j) * 128 + f];
            float wr = W_r[(k4 * 4 + j) * 128 + f];
            #pragma unroll
            for (int r = 0; r < 8; r++) {
                float av = (j == 0) ? a4[r].x : (j == 1) ? a4[r].y : (j == 2) ? a4[r].z : a4[r].w;
                float xv = (j == 0) ? x4[r].x : (j == 1) ? x4[r].y : (j == 2) ? x4[r].z : x4[r].w;
                acc[r] = fmaf(av, wl, acc[r]);
                acc[r] = fmaf(xv, wr, acc[r]);
            }
        }
    }
    #pragma unroll
    for (int r = 0; r < 8; r++)
        h[(size_t)(r0 + r) * 128 + f] = fmaxf(acc[r], 0.0f);
}

// p = h @ W2_l  (128 -> 64). 256 thr = 4 groups x 64 cols, 8 rows/group.
__global__ void __launch_bounds__(256) proj_kernel(
        const float* __restrict__ h, const float* __restrict__ W,
        float* __restrict__ p) {
    __shared__ float s_h[32 * 128];
    const int g = threadIdx.x >> 6;
    const int f = threadIdx.x & 63;
    const int r0 = blockIdx.x * 32;
    {   // 4096 floats = 1024 float4 / 256 threads
        const float4* hv = (const float4*)(h + (size_t)r0 * 128);
        float4* sv = (float4*)s_h;
        for (int t = threadIdx.x; t < 1024; t += 256) sv[t] = hv[t];
    }
    __syncthreads();
    const int rb = g * 8;
    float acc[8] = {0.f, 0.f, 0.f, 0.f, 0.f, 0.f, 0.f, 0.f};
    for (int k4 = 0; k4 < 32; k4++) {
        float4 h4[8];
        #pragma unroll
        for (int r = 0; r < 8; r++)
            h4[r] = *(const float4*)&s_h[(rb + r) * 128 + k4 * 4];
        #pragma unroll
        for (int j = 0; j < 4; j++) {
            float w = W[(k4 * 4 + j) * 64 + f];
            #pragma unroll
            for (int r = 0; r < 8; r++) {
                float hv = (j == 0) ? h4[r].x : (j == 1) ? h4[r].y : (j == 2) ? h4[r].z : h4[r].w;
                acc[r] = fmaf(hv, w, acc[r]);
            }
        }
    }
    #pragma unroll
    for (int r = 0; r < 8; r++)
        p[(size_t)(r0 + rb + r) * 64 + f] = acc[r];
}

// out = agg2 + h @ W2_r + b2. Same structure as proj.
__global__ void __launch_bounds__(256) gemm2_kernel(
        const float* __restrict__ h, const float* __restrict__ agg2,
        const float* __restrict__ W, const float* __restrict__ b,
        float* __restrict__ out) {
    __shared__ float s_h[32 * 128];
    const int g = threadIdx.x >> 6;
    const int f = threadIdx.x & 63;
    const int r0 = blockIdx.x * 32;
    {
        const float4* hv = (const float4*)(h + (size_t)r0 * 128);
        float4* sv = (float4*)s_h;
        for (int t = threadIdx.x; t < 1024; t += 256) sv[t] = hv[t];
    }
    __syncthreads();
    const int rb = g * 8;
    float acc[8];
    const float bf = b[f];
    #pragma unroll
    for (int r = 0; r < 8; r++)
        acc[r] = bf + agg2[(size_t)(r0 + rb + r) * 64 + f];
    for (int k4 = 0; k4 < 32; k4++) {
        float4 h4[8];
        #pragma unroll
        for (int r = 0; r < 8; r++)
            h4[r] = *(const float4*)&s_h[(rb + r) * 128 + k4 * 4];
        #pragma unroll
        for (int j = 0; j < 4; j++) {
            float w = W[(k4 * 4 + j) * 64 + f];
            #pragma unroll
            for (int r = 0; r < 8; r++) {
                float hv = (j == 0) ? h4[r].x : (j == 1) ? h4[r].y : (j == 2) ? h4[r].z : h4[r].w;
                acc[r] = fmaf(hv, w, acc[r]);
            }
        }
    }
    #pragma unroll
    for (int r = 0; r < 8; r++)
        out[(size_t)(r0 + rb + r) * 64 + f] = acc[r];
}

extern "C" void kernel_launch(void* const* d_in, const int* in_sizes, int n_in,
                              void* d_out, int out_size, void* d_ws, size_t ws_size,
                              hipStream_t stream) {
    const float* x    = (const float*)d_in[0];
    const int*   edge = (const int*)d_in[1];
    const float* W1_l = (const float*)d_in[2];
    const float* b1   = (const float*)d_in[3];
    const float* W1_r = (const float*)d_in[4];
    const float* W2_l = (const float*)d_in[5];
    const float* b2   = (const float*)d_in[6];
    const float* W2_r = (const float*)d_in[7];
    float* out = (float*)d_out;

    // ---- workspace layout ----
    int* deg_i  = (int*)d_ws;                 // 100000
    int* cursor = deg_i + 100000;             // 100000
    int* pre    = cursor + 100000;            // 100352
    int* blk    = pre + 100352;               // 128
    int* col    = blk + 128;                  // 1600000
    int* flag   = col + 1600000;              // 1 (+pad to 16B)
    float* inv_deg = (float*)(d_ws) + 1900608;          // 100000 -> pad 100096
    float* agg1    = (float*)(d_ws) + 1900608 + 100096; // 12.8M floats (51.2MB)
    float* h       = agg1 + 12800000;                   // 12.8M floats
    float* p       = agg1;                   // overlay: agg1 dead after gemm1
    float* agg2    = agg1 + 6400000;         // overlay, second half

    detect_kernel<<<1, 256, 0, stream>>>(edge, flag);
    hipMemsetAsync(deg_i, 0, 100000 * sizeof(int), stream);

    deg_count_kernel<<<(N_EDGES + 255) / 256, 256, 0, stream>>>(edge, flag, deg_i);
    scan1_kernel<<<98, 256, 0, stream>>>(deg_i, pre, blk);
    scan2_kernel<<<1, 128, 0, stream>>>(blk);
    scan3_kernel<<<98, 256, 0, stream>>>(pre, blk, deg_i, cursor, inv_deg);
    fill_kernel<<<(N_EDGES + 255) / 256, 256, 0, stream>>>(edge, flag, cursor, col);

    // layer 1: agg1 = inv_deg * segsum(x[src]); h = relu(agg1@W1_l + x@W1_r + b1)
    agg128_kernel<<<12500, 256, 0, stream>>>(cursor, deg_i, col, x, inv_deg, agg1);
    gemm1_kernel<<<12500, 128, 0, stream>>>(agg1, x, W1_l, W1_r, b1, h);

    // layer 2: p = h@W2_l; agg2 = inv_deg * segsum(p[src]); out = agg2 + h@W2_r + b2
    proj_kernel<<<3125, 256, 0, stream>>>(h, W2_l, p);
    agg64_kernel<<<6250, 256, 0, stream>>>(cursor, deg_i, col, p, inv_deg, agg2);
    gemm2_kernel<<<3125, 256, 0, stream>>>(h, agg2, W2_r, b2, out);
}

// Round 3
// 533.644 us; speedup vs baseline: 3.2686x; 1.2518x over previous
//
#include <hip/hip_runtime.h>

#define N_NODES   100000
#define N_EDGES   1600000

typedef __attribute__((ext_vector_type(8))) short short8;
typedef __attribute__((ext_vector_type(4))) float f32x4;

__device__ __forceinline__ unsigned short f2bf(float f) {
    unsigned u = __float_as_uint(f);
    u += 0x7FFF + ((u >> 16) & 1);          // round-to-nearest-even
    return (unsigned short)(u >> 16);
}
__device__ __forceinline__ float bf2f(short s) {
    return __uint_as_float(((unsigned)(unsigned short)s) << 16);
}

// ---------------- edge-index width detector ----------------
__global__ void detect_kernel(const int* __restrict__ e32, int* __restrict__ flag) {
    __shared__ int nz;
    if (threadIdx.x == 0) nz = 0;
    __syncthreads();
    int v = 0;
    for (int i = threadIdx.x; i < 1024; i += 256) v |= e32[2 * i + 1];
    if (v) atomicOr(&nz, 1);
    __syncthreads();
    if (threadIdx.x == 0) *flag = (nz == 0) ? 1 : 0;
}

__device__ __forceinline__ int load_src(const int* e, int is64, int i) {
    return is64 ? e[2 * i] : e[i];
}
__device__ __forceinline__ int load_dst(const int* e, int is64, int i) {
    return is64 ? e[2 * (N_EDGES + i)] : e[N_EDGES + i];
}

// ---------------- CSR construction ----------------
__global__ void deg_count_kernel(const int* __restrict__ e, const int* __restrict__ flag,
                                 int* __restrict__ deg_i) {
    int i = blockIdx.x * blockDim.x + threadIdx.x;
    if (i >= N_EDGES) return;
    int is64 = *flag;
    atomicAdd(&deg_i[load_dst(e, is64, i)], 1);
}

__global__ __launch_bounds__(256) void scan1_kernel(const int* __restrict__ deg_i,
                                                    int* __restrict__ pre,
                                                    int* __restrict__ blk) {
    __shared__ int s[256];
    int base = blockIdx.x * 1024 + threadIdx.x * 4;
    int v0 = 0, v1 = 0, v2 = 0, v3 = 0;
    if (base + 3 < N_NODES) {
        int4 q = *(const int4*)&deg_i[base];
        v0 = q.x; v1 = q.y; v2 = q.z; v3 = q.w;
    } else {
        if (base + 0 < N_NODES) v0 = deg_i[base + 0];
        if (base + 1 < N_NODES) v1 = deg_i[base + 1];
        if (base + 2 < N_NODES) v2 = deg_i[base + 2];
        if (base + 3 < N_NODES) v3 = deg_i[base + 3];
    }
    int tsum = v0 + v1 + v2 + v3;
    s[threadIdx.x] = tsum;
    __syncthreads();
    for (int off = 1; off < 256; off <<= 1) {
        int t = (threadIdx.x >= off) ? s[threadIdx.x - off] : 0;
        __syncthreads();
        s[threadIdx.x] += t;
        __syncthreads();
    }
    int excl = s[threadIdx.x] - tsum;
    pre[base + 0] = excl;
    pre[base + 1] = excl + v0;
    pre[base + 2] = excl + v0 + v1;
    pre[base + 3] = excl + v0 + v1 + v2;
    if (threadIdx.x == 255) blk[blockIdx.x] = s[255];
}

__global__ __launch_bounds__(128) void scan2_kernel(int* __restrict__ blk) {
    __shared__ int s[128];
    int v = (threadIdx.x < 98) ? blk[threadIdx.x] : 0;
    s[threadIdx.x] = v;
    __syncthreads();
    for (int off = 1; off < 128; off <<= 1) {
        int t = (threadIdx.x >= off) ? s[threadIdx.x - off] : 0;
        __syncthreads();
        s[threadIdx.x] += t;
        __syncthreads();
    }
    if (threadIdx.x < 98) blk[threadIdx.x] = s[threadIdx.x] - v;
}

__global__ __launch_bounds__(256) void scan3_kernel(const int* __restrict__ pre,
                                                    const int* __restrict__ blk,
                                                    const int* __restrict__ deg_i,
                                                    int* __restrict__ cursor,
                                                    float* __restrict__ inv_deg) {
    int off = blk[blockIdx.x];
    int base = blockIdx.x * 1024 + threadIdx.x * 4;
    #pragma unroll
    for (int j = 0; j < 4; j++) {
        int idx = base + j;
        if (idx < N_NODES) {
            cursor[idx] = pre[idx] + off;
            inv_deg[idx] = 1.0f / fmaxf((float)deg_i[idx], 1.0f);
        }
    }
}

__global__ void fill_kernel(const int* __restrict__ e, const int* __restrict__ flag,
                            int* __restrict__ cursor, int* __restrict__ col) {
    int i = blockIdx.x * blockDim.x + threadIdx.x;
    if (i >= N_EDGES) return;
    int is64 = *flag;
    int s = load_src(e, is64, i);
    int d = load_dst(e, is64, i);
    int pos = atomicAdd(&cursor[d], 1);
    __builtin_nontemporal_store(s, &col[pos]);
}

// ---------------- bf16 prep ----------------
__global__ __launch_bounds__(256) void prep_x_kernel(const float* __restrict__ x,
                                                     short* __restrict__ xb) {
    int i = (blockIdx.x * 256 + threadIdx.x) * 4;      // 12.8M elems
    float4 v = *(const float4*)&x[i];
    short4 o;
    o.x = (short)f2bf(v.x); o.y = (short)f2bf(v.y);
    o.z = (short)f2bf(v.z); o.w = (short)f2bf(v.w);
    *(short4*)&xb[i] = o;
}

// W1t[n][k] (128x256): k<128 from W1_l[k][n], else W1_r[k-128][n].
// W2lt[n][k] (64x128) = W2_l[k][n]; W2rt likewise.
__global__ __launch_bounds__(256) void prep_w_kernel(
        const float* __restrict__ W1_l, const float* __restrict__ W1_r,
        const float* __restrict__ W2_l, const float* __restrict__ W2_r,
        short* __restrict__ W1t, short* __restrict__ W2lt, short* __restrict__ W2rt) {
    int i = blockIdx.x * 256 + threadIdx.x;            // 49152 total
    if (i < 32768) {
        int n = i >> 8, k = i & 255;
        float v = (k < 128) ? W1_l[k * 128 + n] : W1_r[(k - 128) * 128 + n];
        W1t[i] = (short)f2bf(v);
    } else if (i < 40960) {
        int j = i - 32768, n = j >> 7, k = j & 127;
        W2lt[j] = (short)f2bf(W2_l[k * 64 + n]);
    } else {
        int j = i - 40960, n = j >> 7, k = j & 127;
        W2rt[j] = (short)f2bf(W2_r[k * 64 + n]);
    }
}

// ---------------- gather aggregation (bf16 in, fp32 accum) ----------------
// 128 cols: 16 lanes/node x 8 bf16. 16 nodes / 256-block.
__global__ __launch_bounds__(256) void agg128_kernel(
        const int* __restrict__ cursor, const int* __restrict__ deg_i,
        const int* __restrict__ col, const short* __restrict__ xb,
        const float* __restrict__ inv_deg, short* __restrict__ agg) {
    int node = blockIdx.x * 16 + (threadIdx.x >> 4);
    int lane = threadIdx.x & 15;
    int cnt = deg_i[node];
    int start = cursor[node] - cnt;
    float acc[8] = {0.f};
    int s = (cnt > 0) ? col[start] : 0;
    for (int k = 0; k < cnt; k++) {
        int snext = (k + 1 < cnt) ? col[start + k + 1] : 0;
        short8 v = *(const short8*)(xb + (size_t)s * 128 + lane * 8);
        #pragma unroll
        for (int j = 0; j < 8; j++) acc[j] += bf2f(v[j]);
        s = snext;
    }
    float sc = inv_deg[node];
    short8 o;
    #pragma unroll
    for (int j = 0; j < 8; j++) o[j] = (short)f2bf(acc[j] * sc);
    *(short8*)(agg + (size_t)node * 128 + lane * 8) = o;
}

// 64 cols: 8 lanes/node x 8 bf16. 32 nodes / 256-block. fp32 output.
__global__ __launch_bounds__(256) void agg64_kernel(
        const int* __restrict__ cursor, const int* __restrict__ deg_i,
        const int* __restrict__ col, const short* __restrict__ pb,
        const float* __restrict__ inv_deg, float* __restrict__ agg) {
    int node = blockIdx.x * 32 + (threadIdx.x >> 3);
    int lane = threadIdx.x & 7;
    int cnt = deg_i[node];
    int start = cursor[node] - cnt;
    float acc[8] = {0.f};
    int s = (cnt > 0) ? col[start] : 0;
    for (int k = 0; k < cnt; k++) {
        int snext = (k + 1 < cnt) ? col[start + k + 1] : 0;
        short8 v = *(const short8*)(pb + (size_t)s * 64 + lane * 8);
        #pragma unroll
        for (int j = 0; j < 8; j++) acc[j] += bf2f(v[j]);
        s = snext;
    }
    float sc = inv_deg[node];
    float* dst = agg + (size_t)node * 64 + lane * 8;
    float4 o0 = {acc[0] * sc, acc[1] * sc, acc[2] * sc, acc[3] * sc};
    float4 o1 = {acc[4] * sc, acc[5] * sc, acc[6] * sc, acc[7] * sc};
    *(float4*)dst = o0;
    *(float4*)(dst + 4) = o1;
}

// ---------------- MFMA GEMMs ----------------
// h = relu([agg1|x] @ W1t^T + b1), K=256, N=128. 4 waves x 16 rows = 64 rows/block.
__global__ __launch_bounds__(256) void gemm1_mfma(
        const short* __restrict__ agg1, const short* __restrict__ xb,
        const short* __restrict__ W1t, const float* __restrict__ b1,
        short* __restrict__ h) {
    int wave = threadIdx.x >> 6, lane = threadIdx.x & 63;
    int R0 = blockIdx.x * 64 + wave * 16;
    int m = lane & 15, q = lane >> 4;
    int row = R0 + m; if (row > N_NODES - 1) row = N_NODES - 1;
    const short* arow = agg1 + (size_t)row * 128;
    const short* xrow = xb + (size_t)row * 128;
    f32x4 acc[8];
    #pragma unroll
    for (int t = 0; t < 8; t++) acc[t] = (f32x4){0.f, 0.f, 0.f, 0.f};
    #pragma unroll
    for (int c = 0; c < 8; c++) {
        int kb = c * 32 + q * 8;                       // 0..255
        short8 a = (c < 4) ? *(const short8*)(arow + kb)
                           : *(const short8*)(xrow + kb - 128);
        #pragma unroll
        for (int t = 0; t < 8; t++) {
            short8 b = *(const short8*)(W1t + (t * 16 + m) * 256 + kb);
            acc[t] = __builtin_amdgcn_mfma_f32_16x16x32_bf16(a, b, acc[t], 0, 0, 0);
        }
    }
    #pragma unroll
    for (int t = 0; t < 8; t++) {
        int colc = t * 16 + m;
        float bias = b1[colc];
        #pragma unroll
        for (int r = 0; r < 4; r++) {
            int rr = R0 + q * 4 + r;
            if (rr < N_NODES)
                h[(size_t)rr * 128 + colc] = (short)f2bf(fmaxf(acc[t][r] + bias, 0.f));
        }
    }
}

// p = h @ W2lt^T (K=128, N=64), bf16 out.
__global__ __launch_bounds__(256) void proj_mfma(
        const short* __restrict__ h, const short* __restrict__ W2lt,
        short* __restrict__ p) {
    int wave = threadIdx.x >> 6, lane = threadIdx.x & 63;
    int R0 = blockIdx.x * 64 + wave * 16;
    int m = lane & 15, q = lane >> 4;
    int row = R0 + m; if (row > N_NODES - 1) row = N_NODES - 1;
    const short* hrow = h + (size_t)row * 128;
    f32x4 acc[4];
    #pragma unroll
    for (int t = 0; t < 4; t++) acc[t] = (f32x4){0.f, 0.f, 0.f, 0.f};
    #pragma unroll
    for (int c = 0; c < 4; c++) {
        int kb = c * 32 + q * 8;
        short8 a = *(const short8*)(hrow + kb);
        #pragma unroll
        for (int t = 0; t < 4; t++) {
            short8 b = *(const short8*)(W2lt + (t * 16 + m) * 128 + kb);
            acc[t] = __builtin_amdgcn_mfma_f32_16x16x32_bf16(a, b, acc[t], 0, 0, 0);
        }
    }
    #pragma unroll
    for (int t = 0; t < 4; t++) {
        int colc = t * 16 + m;
        #pragma unroll
        for (int r = 0; r < 4; r++) {
            int rr = R0 + q * 4 + r;
            if (rr < N_NODES)
                p[(size_t)rr * 64 + colc] = (short)f2bf(acc[t][r]);
        }
    }
}

// out = agg2 + h @ W2rt^T + b2 (K=128, N=64), fp32 out.
__global__ __launch_bounds__(256) void gemm2_mfma(
        const short* __restrict__ h, const short* __restrict__ W2rt,
        const float* __restrict__ agg2, const float* __restrict__ b2,
        float* __restrict__ out) {
    int wave = threadIdx.x >> 6, lane = threadIdx.x & 63;
    int R0 = blockIdx.x * 64 + wave * 16;
    int m = lane & 15, q = lane >> 4;
    int row = R0 + m; if (row > N_NODES - 1) row = N_NODES - 1;
    const short* hrow = h + (size_t)row * 128;
    f32x4 acc[4];
    #pragma unroll
    for (int t = 0; t < 4; t++) acc[t] = (f32x4){0.f, 0.f, 0.f, 0.f};
    #pragma unroll
    for (int c = 0; c < 4; c++) {
        int kb = c * 32 + q * 8;
        short8 a = *(const short8*)(hrow + kb);
        #pragma unroll
        for (int t = 0; t < 4; t++) {
            short8 b = *(const short8*)(W2rt + (t * 16 + m) * 128 + kb);
            acc[t] = __builtin_amdgcn_mfma_f32_16x16x32_bf16(a, b, acc[t], 0, 0, 0);
        }
    }
    #pragma unroll
    for (int t = 0; t < 4; t++) {
        int colc = t * 16 + m;
        float bias = b2[colc];
        #pragma unroll
        for (int r = 0; r < 4; r++) {
            int rr = R0 + q * 4 + r;
            if (rr < N_NODES)
                out[(size_t)rr * 64 + colc] = acc[t][r] + bias + agg2[(size_t)rr * 64 + colc];
        }
    }
}

extern "C" void kernel_launch(void* const* d_in, const int* in_sizes, int n_in,
                              void* d_out, int out_size, void* d_ws, size_t ws_size,
                              hipStream_t stream) {
    const float* x    = (const float*)d_in[0];
    const int*   edge = (const int*)d_in[1];
    const float* W1_l = (const float*)d_in[2];
    const float* b1   = (const float*)d_in[3];
    const float* W1_r = (const float*)d_in[4];
    const float* W2_l = (const float*)d_in[5];
    const float* b2   = (const float*)d_in[6];
    const float* W2_r = (const float*)d_in[7];
    float* out = (float*)d_out;

    // ---- workspace layout (84.9 MB total) ----
    int* deg_i  = (int*)d_ws;                 // 100000
    int* cursor = deg_i + 100000;             // 100000
    int* pre    = cursor + 100000;            // 100352
    int* blk    = pre + 100352;               // 128
    int* col    = blk + 128;                  // 1600000
    int* flag   = col + 1600000;              // 1, pad to int offset 1900544
    float* inv_deg = (float*)d_ws + 1900544;  // 100000, pad to 2000576
    short* xb   = (short*)((float*)d_ws + 2000576);  // 12.8M bf16 (x)
    short* hb   = xb + 12800000;                     // 12.8M bf16 (h)
    short* ag1  = hb + 12800000;                     // 12.8M bf16 (agg1; p overlays)
    short* W1t  = ag1 + 12800000;                    // 32768
    short* W2lt = W1t + 32768;                       // 8192
    short* W2rt = W2lt + 8192;                       // 8192
    short* pb   = ag1;                               // overlay: agg1 dead after gemm1
    float* agg2 = (float*)xb;                        // overlay: xb dead after gemm1

    detect_kernel<<<1, 256, 0, stream>>>(edge, flag);
    hipMemsetAsync(deg_i, 0, 100000 * sizeof(int), stream);

    deg_count_kernel<<<(N_EDGES + 255) / 256, 256, 0, stream>>>(edge, flag, deg_i);
    scan1_kernel<<<98, 256, 0, stream>>>(deg_i, pre, blk);
    scan2_kernel<<<1, 128, 0, stream>>>(blk);
    scan3_kernel<<<98, 256, 0, stream>>>(pre, blk, deg_i, cursor, inv_deg);
    fill_kernel<<<(N_EDGES + 255) / 256, 256, 0, stream>>>(edge, flag, cursor, col);

    prep_x_kernel<<<12500, 256, 0, stream>>>(x, xb);
    prep_w_kernel<<<192, 256, 0, stream>>>(W1_l, W1_r, W2_l, W2_r, W1t, W2lt, W2rt);

    // layer 1
    agg128_kernel<<<6250, 256, 0, stream>>>(cursor, deg_i, col, xb, inv_deg, ag1);
    gemm1_mfma<<<1563, 256, 0, stream>>>(ag1, xb, W1t, b1, hb);

    // layer 2
    proj_mfma<<<1563, 256, 0, stream>>>(hb, W2lt, pb);
    agg64_kernel<<<3125, 256, 0, stream>>>(cursor, deg_i, col, pb, inv_deg, agg2);
    gemm2_mfma<<<1563, 256, 0, stream>>>(hb, W2rt, agg2, b2, out);
}

// Round 4
// 409.495 us; speedup vs baseline: 4.2595x; 1.3032x over previous
//
#include <hip/hip_runtime.h>

#define N_NODES   100000
#define N_EDGES   1600000
#define BSHIFT    9
#define NB        196        // ceil(100000 / 512)

typedef __attribute__((ext_vector_type(8))) short short8;
typedef __attribute__((ext_vector_type(4))) float f32x4;

__device__ __forceinline__ unsigned short f2bf(float f) {
    unsigned u = __float_as_uint(f);
    u += 0x7FFF + ((u >> 16) & 1);          // round-to-nearest-even
    return (unsigned short)(u >> 16);
}
__device__ __forceinline__ float bf2f(short s) {
    return __uint_as_float(((unsigned)(unsigned short)s) << 16);
}

// ---------------- edge-index width detector ----------------
__global__ void detect_kernel(const int* __restrict__ e32, int* __restrict__ flag) {
    __shared__ int nz;
    if (threadIdx.x == 0) nz = 0;
    __syncthreads();
    int v = 0;
    for (int i = threadIdx.x; i < 1024; i += 256) v |= e32[2 * i + 1];
    if (v) atomicOr(&nz, 1);
    __syncthreads();
    if (threadIdx.x == 0) *flag = (nz == 0) ? 1 : 0;
}

__device__ __forceinline__ int load_src(const int* e, int is64, int i) {
    return is64 ? e[2 * i] : e[i];
}
__device__ __forceinline__ int load_dst(const int* e, int is64, int i) {
    return is64 ? e[2 * (N_EDGES + i)] : e[N_EDGES + i];
}

// ---------------- bucketed CSR build ----------------
// Phase A: global bucket histogram via per-block LDS histograms.
__global__ __launch_bounds__(256) void bucket_count_kernel(
        const int* __restrict__ e, const int* __restrict__ flag,
        int* __restrict__ bcnt) {
    __shared__ int s_cnt[NB];
    for (int t = threadIdx.x; t < NB; t += 256) s_cnt[t] = 0;
    __syncthreads();
    int is64 = *flag;
    int i0 = blockIdx.x * 4096;
    int n = min(4096, N_EDGES - i0);
    for (int t = 0; t < 16; t++) {
        int k = t * 256 + threadIdx.x;
        if (k < n) {
            int d = load_dst(e, is64, i0 + k);
            atomicAdd(&s_cnt[d >> BSHIFT], 1);
        }
    }
    __syncthreads();
    for (int t = threadIdx.x; t < NB; t += 256)
        if (s_cnt[t]) atomicAdd(&bcnt[t], s_cnt[t]);
}

// Phase A2: scan bucket counts -> starts, init cursors.
__global__ __launch_bounds__(256) void bucket_scan_kernel(
        const int* __restrict__ bcnt, int* __restrict__ bstart, int* __restrict__ bcur) {
    __shared__ int s[256];
    int v = (threadIdx.x < NB) ? bcnt[threadIdx.x] : 0;
    s[threadIdx.x] = v;
    __syncthreads();
    for (int off = 1; off < 256; off <<= 1) {
        int t = (threadIdx.x >= off) ? s[threadIdx.x - off] : 0;
        __syncthreads();
        s[threadIdx.x] += t;
        __syncthreads();
    }
    if (threadIdx.x < NB) {
        int st = s[threadIdx.x] - v;
        bstart[threadIdx.x] = st;
        bcur[threadIdx.x] = st;
    }
}

// Phase B: bucket-sort 4096 edges per block in LDS, coalesced copy-out of pairs.
__global__ __launch_bounds__(256) void binscat_kernel(
        const int* __restrict__ e, const int* __restrict__ flag,
        int* __restrict__ bcur, int2* __restrict__ pairs) {
    __shared__ int2 s_pairs[4096];
    __shared__ int s_cnt[256], s_off[256], s_base[256], s_cur[256];
    const int tid = threadIdx.x;
    s_cnt[tid] = 0;
    __syncthreads();
    int is64 = *flag;
    int i0 = blockIdx.x * 4096;
    int n = min(4096, N_EDGES - i0);
    // pass 1: count buckets
    for (int t = 0; t < 16; t++) {
        int k = t * 256 + tid;
        if (k < n) {
            int d = load_dst(e, is64, i0 + k);
            atomicAdd(&s_cnt[d >> BSHIFT], 1);
        }
    }
    __syncthreads();
    // exclusive scan of s_cnt into s_off (Hillis-Steele)
    int v = s_cnt[tid];
    s_off[tid] = v;
    __syncthreads();
    for (int off = 1; off < 256; off <<= 1) {
        int t = (tid >= off) ? s_off[tid - off] : 0;
        __syncthreads();
        s_off[tid] += t;
        __syncthreads();
    }
    int excl = s_off[tid] - v;
    int gb = 0;
    if (tid < NB && v > 0) gb = atomicAdd(&bcur[tid], v);
    s_off[tid] = excl;      // own slot only; all cross-reads finished above
    s_base[tid] = gb;
    s_cur[tid] = excl;
    __syncthreads();
    // pass 2: scatter into LDS ordered by bucket
    for (int t = 0; t < 16; t++) {
        int k = t * 256 + tid;
        if (k < n) {
            int s = load_src(e, is64, i0 + k);
            int d = load_dst(e, is64, i0 + k);
            int pos = atomicAdd(&s_cur[d >> BSHIFT], 1);
            s_pairs[pos] = (int2){s, d};
        }
    }
    __syncthreads();
    // coalesced copy-out: consecutive j within a bucket -> consecutive global
    for (int j = tid; j < n; j += 256) {
        int2 pr = s_pairs[j];
        int b = pr.y >> BSHIFT;
        pairs[s_base[b] + (j - s_off[b])] = pr;
    }
}

// Phase C1: per-bucket degree via LDS counters.
__global__ __launch_bounds__(256) void bucket_deg_kernel(
        const int* __restrict__ bstart, const int* __restrict__ bcnt,
        const int2* __restrict__ pairs, int* __restrict__ deg_i) {
    __shared__ int ldeg[512];
    int b = blockIdx.x;
    for (int t = threadIdx.x; t < 512; t += 256) ldeg[t] = 0;
    __syncthreads();
    int p0 = bstart[b], cnt = bcnt[b];
    int nbase = b << BSHIFT;
    for (int j = threadIdx.x; j < cnt; j += 256) {
        int d = pairs[p0 + j].y;
        atomicAdd(&ldeg[d - nbase], 1);
    }
    __syncthreads();
    for (int t = threadIdx.x; t < 512; t += 256) {
        int idx = nbase + t;
        if (idx < N_NODES) deg_i[idx] = ldeg[t];
    }
}

// node scan (row starts) -- unchanged 3-phase scan over deg_i
__global__ __launch_bounds__(256) void scan1_kernel(const int* __restrict__ deg_i,
                                                    int* __restrict__ pre,
                                                    int* __restrict__ blk) {
    __shared__ int s[256];
    int base = blockIdx.x * 1024 + threadIdx.x * 4;
    int v0 = 0, v1 = 0, v2 = 0, v3 = 0;
    if (base + 3 < N_NODES) {
        int4 q = *(const int4*)&deg_i[base];
        v0 = q.x; v1 = q.y; v2 = q.z; v3 = q.w;
    } else {
        if (base + 0 < N_NODES) v0 = deg_i[base + 0];
        if (base + 1 < N_NODES) v1 = deg_i[base + 1];
        if (base + 2 < N_NODES) v2 = deg_i[base + 2];
        if (base + 3 < N_NODES) v3 = deg_i[base + 3];
    }
    int tsum = v0 + v1 + v2 + v3;
    s[threadIdx.x] = tsum;
    __syncthreads();
    for (int off = 1; off < 256; off <<= 1) {
        int t = (threadIdx.x >= off) ? s[threadIdx.x - off] : 0;
        __syncthreads();
        s[threadIdx.x] += t;
        __syncthreads();
    }
    int excl = s[threadIdx.x] - tsum;
    pre[base + 0] = excl;
    pre[base + 1] = excl + v0;
    pre[base + 2] = excl + v0 + v1;
    pre[base + 3] = excl + v0 + v1 + v2;
    if (threadIdx.x == 255) blk[blockIdx.x] = s[255];
}

__global__ __launch_bounds__(128) void scan2_kernel(int* __restrict__ blk) {
    __shared__ int s[128];
    int v = (threadIdx.x < 98) ? blk[threadIdx.x] : 0;
    s[threadIdx.x] = v;
    __syncthreads();
    for (int off = 1; off < 128; off <<= 1) {
        int t = (threadIdx.x >= off) ? s[threadIdx.x - off] : 0;
        __syncthreads();
        s[threadIdx.x] += t;
        __syncthreads();
    }
    if (threadIdx.x < 98) blk[threadIdx.x] = s[threadIdx.x] - v;
}

__global__ __launch_bounds__(256) void scan3_kernel(const int* __restrict__ pre,
                                                    const int* __restrict__ blk,
                                                    const int* __restrict__ deg_i,
                                                    int* __restrict__ cursor,
                                                    float* __restrict__ inv_deg) {
    int off = blk[blockIdx.x];
    int base = blockIdx.x * 1024 + threadIdx.x * 4;
    #pragma unroll
    for (int j = 0; j < 4; j++) {
        int idx = base + j;
        if (idx < N_NODES) {
            cursor[idx] = pre[idx] + off;        // row START (immutable)
            inv_deg[idx] = 1.0f / fmaxf((float)deg_i[idx], 1.0f);
        }
    }
}

// Phase C2: fill col with per-bucket LDS cursors; writes stay in one L2 region.
__global__ __launch_bounds__(256) void bucket_fill_kernel(
        const int* __restrict__ bstart, const int* __restrict__ bcnt,
        const int2* __restrict__ pairs, const int* __restrict__ cursor,
        int* __restrict__ col) {
    __shared__ int lcur[512];
    int b = blockIdx.x;
    int nbase = b << BSHIFT;
    for (int t = threadIdx.x; t < 512; t += 256) {
        int idx = nbase + t;
        lcur[t] = (idx < N_NODES) ? cursor[idx] : 0;
    }
    __syncthreads();
    int p0 = bstart[b], cnt = bcnt[b];
    for (int j = threadIdx.x; j < cnt; j += 256) {
        int2 pr = pairs[p0 + j];
        int pos = atomicAdd(&lcur[pr.y - nbase], 1);
        col[pos] = pr.x;
    }
}

// ---------------- bf16 prep ----------------
__global__ __launch_bounds__(256) void prep_x_kernel(const float* __restrict__ x,
                                                     short* __restrict__ xb) {
    int i = (blockIdx.x * 256 + threadIdx.x) * 4;
    float4 v = *(const float4*)&x[i];
    short4 o;
    o.x = (short)f2bf(v.x); o.y = (short)f2bf(v.y);
    o.z = (short)f2bf(v.z); o.w = (short)f2bf(v.w);
    *(short4*)&xb[i] = o;
}

__global__ __launch_bounds__(256) void prep_w_kernel(
        const float* __restrict__ W1_l, const float* __restrict__ W1_r,
        const float* __restrict__ W2_l, const float* __restrict__ W2_r,
        short* __restrict__ W1t, short* __restrict__ W2lt, short* __restrict__ W2rt) {
    int i = blockIdx.x * 256 + threadIdx.x;
    if (i < 32768) {
        int n = i >> 8, k = i & 255;
        float v = (k < 128) ? W1_l[k * 128 + n] : W1_r[(k - 128) * 128 + n];
        W1t[i] = (short)f2bf(v);
    } else if (i < 40960) {
        int j = i - 32768, n = j >> 7, k = j & 127;
        W2lt[j] = (short)f2bf(W2_l[k * 64 + n]);
    } else {
        int j = i - 40960, n = j >> 7, k = j & 127;
        W2rt[j] = (short)f2bf(W2_r[k * 64 + n]);
    }
}

// ---------------- gather aggregation (bf16 in, fp32 accum) ----------------
__global__ __launch_bounds__(256) void agg128_kernel(
        const int* __restrict__ cursor, const int* __restrict__ deg_i,
        const int* __restrict__ col, const short* __restrict__ xb,
        const float* __restrict__ inv_deg, short* __restrict__ agg) {
    int node = blockIdx.x * 16 + (threadIdx.x >> 4);
    int lane = threadIdx.x & 15;
    int cnt = deg_i[node];
    int start = cursor[node];
    float acc[8] = {0.f};
    int s = (cnt > 0) ? col[start] : 0;
    for (int k = 0; k < cnt; k++) {
        int snext = (k + 1 < cnt) ? col[start + k + 1] : 0;
        short8 v = *(const short8*)(xb + (size_t)s * 128 + lane * 8);
        #pragma unroll
        for (int j = 0; j < 8; j++) acc[j] += bf2f(v[j]);
        s = snext;
    }
    float sc = inv_deg[node];
    short8 o;
    #pragma unroll
    for (int j = 0; j < 8; j++) o[j] = (short)f2bf(acc[j] * sc);
    *(short8*)(agg + (size_t)node * 128 + lane * 8) = o;
}

__global__ __launch_bounds__(256) void agg64_kernel(
        const int* __restrict__ cursor, const int* __restrict__ deg_i,
        const int* __restrict__ col, const short* __restrict__ pb,
        const float* __restrict__ inv_deg, float* __restrict__ agg) {
    int node = blockIdx.x * 32 + (threadIdx.x >> 3);
    int lane = threadIdx.x & 7;
    int cnt = deg_i[node];
    int start = cursor[node];
    float acc[8] = {0.f};
    int s = (cnt > 0) ? col[start] : 0;
    for (int k = 0; k < cnt; k++) {
        int snext = (k + 1 < cnt) ? col[start + k + 1] : 0;
        short8 v = *(const short8*)(pb + (size_t)s * 64 + lane * 8);
        #pragma unroll
        for (int j = 0; j < 8; j++) acc[j] += bf2f(v[j]);
        s = snext;
    }
    float sc = inv_deg[node];
    float* dst = agg + (size_t)node * 64 + lane * 8;
    float4 o0 = {acc[0] * sc, acc[1] * sc, acc[2] * sc, acc[3] * sc};
    float4 o1 = {acc[4] * sc, acc[5] * sc, acc[6] * sc, acc[7] * sc};
    *(float4*)dst = o0;
    *(float4*)(dst + 4) = o1;
}

// ---------------- MFMA GEMMs ----------------
__global__ __launch_bounds__(256) void gemm1_mfma(
        const short* __restrict__ agg1, const short* __restrict__ xb,
        const short* __restrict__ W1t, const float* __restrict__ b1,
        short* __restrict__ h) {
    int wave = threadIdx.x >> 6, lane = threadIdx.x & 63;
    int R0 = blockIdx.x * 64 + wave * 16;
    int m = lane & 15, q = lane >> 4;
    int row = R0 + m; if (row > N_NODES - 1) row = N_NODES - 1;
    const short* arow = agg1 + (size_t)row * 128;
    const short* xrow = xb + (size_t)row * 128;
    f32x4 acc[8];
    #pragma unroll
    for (int t = 0; t < 8; t++) acc[t] = (f32x4){0.f, 0.f, 0.f, 0.f};
    #pragma unroll
    for (int c = 0; c < 8; c++) {
        int kb = c * 32 + q * 8;
        short8 a = (c < 4) ? *(const short8*)(arow + kb)
                           : *(const short8*)(xrow + kb - 128);
        #pragma unroll
        for (int t = 0; t < 8; t++) {
            short8 b = *(const short8*)(W1t + (t * 16 + m) * 256 + kb);
            acc[t] = __builtin_amdgcn_mfma_f32_16x16x32_bf16(a, b, acc[t], 0, 0, 0);
        }
    }
    #pragma unroll
    for (int t = 0; t < 8; t++) {
        int colc = t * 16 + m;
        float bias = b1[colc];
        #pragma unroll
        for (int r = 0; r < 4; r++) {
            int rr = R0 + q * 4 + r;
            if (rr < N_NODES)
                h[(size_t)rr * 128 + colc] = (short)f2bf(fmaxf(acc[t][r] + bias, 0.f));
        }
    }
}

__global__ __launch_bounds__(256) void proj_mfma(
        const short* __restrict__ h, const short* __restrict__ W2lt,
        short* __restrict__ p) {
    int wave = threadIdx.x >> 6, lane = threadIdx.x & 63;
    int R0 = blockIdx.x * 64 + wave * 16;
    int m = lane & 15, q = lane >> 4;
    int row = R0 + m; if (row > N_NODES - 1) row = N_NODES - 1;
    const short* hrow = h + (size_t)row * 128;
    f32x4 acc[4];
    #pragma unroll
    for (int t = 0; t < 4; t++) acc[t] = (f32x4){0.f, 0.f, 0.f, 0.f};
    #pragma unroll
    for (int c = 0; c < 4; c++) {
        int kb = c * 32 + q * 8;
        short8 a = *(const short8*)(hrow + kb);
        #pragma unroll
        for (int t = 0; t < 4; t++) {
            short8 b = *(const short8*)(W2lt + (t * 16 + m) * 128 + kb);
            acc[t] = __builtin_amdgcn_mfma_f32_16x16x32_bf16(a, b, acc[t], 0, 0, 0);
        }
    }
    #pragma unroll
    for (int t = 0; t < 4; t++) {
        int colc = t * 16 + m;
        #pragma unroll
        for (int r = 0; r < 4; r++) {
            int rr = R0 + q * 4 + r;
            if (rr < N_NODES)
                p[(size_t)rr * 64 + colc] = (short)f2bf(acc[t][r]);
        }
    }
}

__global__ __launch_bounds__(256) void gemm2_mfma(
        const short* __restrict__ h, const short* __restrict__ W2rt,
        const float* __restrict__ agg2, const float* __restrict__ b2,
        float* __restrict__ out) {
    int wave = threadIdx.x >> 6, lane = threadIdx.x & 63;
    int R0 = blockIdx.x * 64 + wave * 16;
    int m = lane & 15, q = lane >> 4;
    int row = R0 + m; if (row > N_NODES - 1) row = N_NODES - 1;
    const short* hrow = h + (size_t)row * 128;
    f32x4 acc[4];
    #pragma unroll
    for (int t = 0; t < 4; t++) acc[t] = (f32x4){0.f, 0.f, 0.f, 0.f};
    #pragma unroll
    for (int c = 0; c < 4; c++) {
        int kb = c * 32 + q * 8;
        short8 a = *(const short8*)(hrow + kb);
        #pragma unroll
        for (int t = 0; t < 4; t++) {
            short8 b = *(const short8*)(W2rt + (t * 16 + m) * 128 + kb);
            acc[t] = __builtin_amdgcn_mfma_f32_16x16x32_bf16(a, b, acc[t], 0, 0, 0);
        }
    }
    #pragma unroll
    for (int t = 0; t < 4; t++) {
        int colc = t * 16 + m;
        float bias = b2[colc];
        #pragma unroll
        for (int r = 0; r < 4; r++) {
            int rr = R0 + q * 4 + r;
            if (rr < N_NODES)
                out[(size_t)rr * 64 + colc] = acc[t][r] + bias + agg2[(size_t)rr * 64 + colc];
        }
    }
}

extern "C" void kernel_launch(void* const* d_in, const int* in_sizes, int n_in,
                              void* d_out, int out_size, void* d_ws, size_t ws_size,
                              hipStream_t stream) {
    const float* x    = (const float*)d_in[0];
    const int*   edge = (const int*)d_in[1];
    const float* W1_l = (const float*)d_in[2];
    const float* b1   = (const float*)d_in[3];
    const float* W1_r = (const float*)d_in[4];
    const float* W2_l = (const float*)d_in[5];
    const float* b2   = (const float*)d_in[6];
    const float* W2_r = (const float*)d_in[7];
    float* out = (float*)d_out;

    // ---- workspace layout (~97.7 MB) ----
    int* iw = (int*)d_ws;
    int* deg_i  = iw;                    // 100000
    int* cursor = iw + 100000;           // 100000 (row starts)
    int* pre    = iw + 200000;           // 100352
    int* blk    = iw + 300352;           // 128
    int* col    = iw + 300480;           // 1600000
    int* bcnt   = iw + 1900480;          // 256
    int* bstart = iw + 1900736;          // 256
    int* bcur   = iw + 1900992;          // 256
    int* flag   = iw + 1901248;          // pad to 1901312
    float* inv_deg = (float*)iw + 1901312;   // 100096
    int2*  pairs   = (int2*)(iw + 2001408); // 1.6M int2 (12.8 MB), 8B-aligned
    short* xb   = (short*)(iw + 5201408);    // 12.8M bf16
    short* hb   = xb + 12800000;             // 12.8M bf16
    short* ag1  = hb + 12800000;             // 12.8M bf16
    short* W1t  = ag1 + 12800000;            // 32768
    short* W2lt = W1t + 32768;               // 8192
    short* W2rt = W2lt + 8192;               // 8192
    short* pb   = ag1;                       // overlay: agg1 dead after gemm1
    float* agg2 = (float*)xb;                // overlay: xb dead after gemm1

    detect_kernel<<<1, 256, 0, stream>>>(edge, flag);
    hipMemsetAsync(bcnt, 0, NB * sizeof(int), stream);

    // bucketed CSR build
    bucket_count_kernel<<<391, 256, 0, stream>>>(edge, flag, bcnt);
    bucket_scan_kernel<<<1, 256, 0, stream>>>(bcnt, bstart, bcur);
    binscat_kernel<<<391, 256, 0, stream>>>(edge, flag, bcur, pairs);
    bucket_deg_kernel<<<NB, 256, 0, stream>>>(bstart, bcnt, pairs, deg_i);
    scan1_kernel<<<98, 256, 0, stream>>>(deg_i, pre, blk);
    scan2_kernel<<<1, 128, 0, stream>>>(blk);
    scan3_kernel<<<98, 256, 0, stream>>>(pre, blk, deg_i, cursor, inv_deg);
    bucket_fill_kernel<<<NB, 256, 0, stream>>>(bstart, bcnt, pairs, cursor, col);

    prep_x_kernel<<<12500, 256, 0, stream>>>(x, xb);
    prep_w_kernel<<<192, 256, 0, stream>>>(W1_l, W1_r, W2_l, W2_r, W1t, W2lt, W2rt);

    // layer 1
    agg128_kernel<<<6250, 256, 0, stream>>>(cursor, deg_i, col, xb, inv_deg, ag1);
    gemm1_mfma<<<1563, 256, 0, stream>>>(ag1, xb, W1t, b1, hb);

    // layer 2
    proj_mfma<<<1563, 256, 0, stream>>>(hb, W2lt, pb);
    agg64_kernel<<<3125, 256, 0, stream>>>(cursor, deg_i, col, pb, inv_deg, agg2);
    gemm2_mfma<<<1563, 256, 0, stream>>>(hb, W2rt, agg2, b2, out);
}

// Round 5
// 347.042 us; speedup vs baseline: 5.0261x; 1.1800x over previous
//
#include <hip/hip_runtime.h>

#define N_NODES   100000
#define N_EDGES   1600000
#define BSHIFT    9
#define NB        196        // ceil(100000 / 512)

typedef __attribute__((ext_vector_type(8))) short short8;
typedef __attribute__((ext_vector_type(4))) float f32x4;

__device__ __forceinline__ unsigned short f2bf(float f) {
    unsigned u = __float_as_uint(f);
    u += 0x7FFF + ((u >> 16) & 1);          // round-to-nearest-even
    return (unsigned short)(u >> 16);
}
__device__ __forceinline__ float bf2f(short s) {
    return __uint_as_float(((unsigned)(unsigned short)s) << 16);
}

// ---------------- edge-index width detector ----------------
__global__ void detect_kernel(const int* __restrict__ e32, int* __restrict__ flag) {
    __shared__ int nz;
    if (threadIdx.x == 0) nz = 0;
    __syncthreads();
    int v = 0;
    for (int i = threadIdx.x; i < 1024; i += 256) v |= e32[2 * i + 1];
    if (v) atomicOr(&nz, 1);
    __syncthreads();
    if (threadIdx.x == 0) *flag = (nz == 0) ? 1 : 0;
}

__device__ __forceinline__ int load_src(const int* e, int is64, int i) {
    return is64 ? e[2 * i] : e[i];
}
__device__ __forceinline__ int load_dst(const int* e, int is64, int i) {
    return is64 ? e[2 * (N_EDGES + i)] : e[N_EDGES + i];
}

// ---------------- bucketed CSR build ----------------
__global__ __launch_bounds__(256) void bucket_count_kernel(
        const int* __restrict__ e, const int* __restrict__ flag,
        int* __restrict__ bcnt) {
    __shared__ int s_cnt[NB];
    for (int t = threadIdx.x; t < NB; t += 256) s_cnt[t] = 0;
    __syncthreads();
    int is64 = *flag;
    int i0 = blockIdx.x * 4096;
    int n = min(4096, N_EDGES - i0);
    for (int t = 0; t < 16; t++) {
        int k = t * 256 + threadIdx.x;
        if (k < n) {
            int d = load_dst(e, is64, i0 + k);
            atomicAdd(&s_cnt[d >> BSHIFT], 1);
        }
    }
    __syncthreads();
    for (int t = threadIdx.x; t < NB; t += 256)
        if (s_cnt[t]) atomicAdd(&bcnt[t], s_cnt[t]);
}

__global__ __launch_bounds__(256) void bucket_scan_kernel(
        const int* __restrict__ bcnt, int* __restrict__ bstart, int* __restrict__ bcur) {
    __shared__ int s[256];
    int v = (threadIdx.x < NB) ? bcnt[threadIdx.x] : 0;
    s[threadIdx.x] = v;
    __syncthreads();
    for (int off = 1; off < 256; off <<= 1) {
        int t = (threadIdx.x >= off) ? s[threadIdx.x - off] : 0;
        __syncthreads();
        s[threadIdx.x] += t;
        __syncthreads();
    }
    if (threadIdx.x < NB) {
        int st = s[threadIdx.x] - v;
        bstart[threadIdx.x] = st;
        bcur[threadIdx.x] = st;
    }
}

__global__ __launch_bounds__(256) void binscat_kernel(
        const int* __restrict__ e, const int* __restrict__ flag,
        int* __restrict__ bcur, int2* __restrict__ pairs) {
    __shared__ int2 s_pairs[4096];
    __shared__ int s_cnt[256], s_off[256], s_base[256], s_cur[256];
    const int tid = threadIdx.x;
    s_cnt[tid] = 0;
    __syncthreads();
    int is64 = *flag;
    int i0 = blockIdx.x * 4096;
    int n = min(4096, N_EDGES - i0);
    for (int t = 0; t < 16; t++) {
        int k = t * 256 + tid;
        if (k < n) {
            int d = load_dst(e, is64, i0 + k);
            atomicAdd(&s_cnt[d >> BSHIFT], 1);
        }
    }
    __syncthreads();
    int v = s_cnt[tid];
    s_off[tid] = v;
    __syncthreads();
    for (int off = 1; off < 256; off <<= 1) {
        int t = (tid >= off) ? s_off[tid - off] : 0;
        __syncthreads();
        s_off[tid] += t;
        __syncthreads();
    }
    int excl = s_off[tid] - v;
    int gb = 0;
    if (tid < NB && v > 0) gb = atomicAdd(&bcur[tid], v);
    s_off[tid] = excl;
    s_base[tid] = gb;
    s_cur[tid] = excl;
    __syncthreads();
    for (int t = 0; t < 16; t++) {
        int k = t * 256 + tid;
        if (k < n) {
            int s = load_src(e, is64, i0 + k);
            int d = load_dst(e, is64, i0 + k);
            int pos = atomicAdd(&s_cur[d >> BSHIFT], 1);
            s_pairs[pos] = (int2){s, d};
        }
    }
    __syncthreads();
    for (int j = tid; j < n; j += 256) {
        int2 pr = s_pairs[j];
        int b = pr.y >> BSHIFT;
        pairs[s_base[b] + (j - s_off[b])] = pr;
    }
}

__global__ __launch_bounds__(256) void bucket_deg_kernel(
        const int* __restrict__ bstart, const int* __restrict__ bcnt,
        const int2* __restrict__ pairs, int* __restrict__ deg_i) {
    __shared__ int ldeg[512];
    int b = blockIdx.x;
    for (int t = threadIdx.x; t < 512; t += 256) ldeg[t] = 0;
    __syncthreads();
    int p0 = bstart[b], cnt = bcnt[b];
    int nbase = b << BSHIFT;
    for (int j = threadIdx.x; j < cnt; j += 256) {
        int d = pairs[p0 + j].y;
        atomicAdd(&ldeg[d - nbase], 1);
    }
    __syncthreads();
    for (int t = threadIdx.x; t < 512; t += 256) {
        int idx = nbase + t;
        if (idx < N_NODES) deg_i[idx] = ldeg[t];
    }
}

__global__ __launch_bounds__(256) void scan1_kernel(const int* __restrict__ deg_i,
                                                    int* __restrict__ pre,
                                                    int* __restrict__ blk) {
    __shared__ int s[256];
    int base = blockIdx.x * 1024 + threadIdx.x * 4;
    int v0 = 0, v1 = 0, v2 = 0, v3 = 0;
    if (base + 3 < N_NODES) {
        int4 q = *(const int4*)&deg_i[base];
        v0 = q.x; v1 = q.y; v2 = q.z; v3 = q.w;
    } else {
        if (base + 0 < N_NODES) v0 = deg_i[base + 0];
        if (base + 1 < N_NODES) v1 = deg_i[base + 1];
        if (base + 2 < N_NODES) v2 = deg_i[base + 2];
        if (base + 3 < N_NODES) v3 = deg_i[base + 3];
    }
    int tsum = v0 + v1 + v2 + v3;
    s[threadIdx.x] = tsum;
    __syncthreads();
    for (int off = 1; off < 256; off <<= 1) {
        int t = (threadIdx.x >= off) ? s[threadIdx.x - off] : 0;
        __syncthreads();
        s[threadIdx.x] += t;
        __syncthreads();
    }
    int excl = s[threadIdx.x] - tsum;
    pre[base + 0] = excl;
    pre[base + 1] = excl + v0;
    pre[base + 2] = excl + v0 + v1;
    pre[base + 3] = excl + v0 + v1 + v2;
    if (threadIdx.x == 255) blk[blockIdx.x] = s[255];
}

__global__ __launch_bounds__(128) void scan2_kernel(int* __restrict__ blk) {
    __shared__ int s[128];
    int v = (threadIdx.x < 98) ? blk[threadIdx.x] : 0;
    s[threadIdx.x] = v;
    __syncthreads();
    for (int off = 1; off < 128; off <<= 1) {
        int t = (threadIdx.x >= off) ? s[threadIdx.x - off] : 0;
        __syncthreads();
        s[threadIdx.x] += t;
        __syncthreads();
    }
    if (threadIdx.x < 98) blk[threadIdx.x] = s[threadIdx.x] - v;
}

__global__ __launch_bounds__(256) void scan3_kernel(const int* __restrict__ pre,
                                                    const int* __restrict__ blk,
                                                    const int* __restrict__ deg_i,
                                                    int* __restrict__ cursor,
                                                    float* __restrict__ inv_deg) {
    int off = blk[blockIdx.x];
    int base = blockIdx.x * 1024 + threadIdx.x * 4;
    #pragma unroll
    for (int j = 0; j < 4; j++) {
        int idx = base + j;
        if (idx < N_NODES) {
            cursor[idx] = pre[idx] + off;        // row START (immutable)
            inv_deg[idx] = 1.0f / fmaxf((float)deg_i[idx], 1.0f);
        }
    }
}

__global__ __launch_bounds__(256) void bucket_fill_kernel(
        const int* __restrict__ bstart, const int* __restrict__ bcnt,
        const int2* __restrict__ pairs, const int* __restrict__ cursor,
        int* __restrict__ col) {
    __shared__ int lcur[512];
    int b = blockIdx.x;
    int nbase = b << BSHIFT;
    for (int t = threadIdx.x; t < 512; t += 256) {
        int idx = nbase + t;
        lcur[t] = (idx < N_NODES) ? cursor[idx] : 0;
    }
    __syncthreads();
    int p0 = bstart[b], cnt = bcnt[b];
    for (int j = threadIdx.x; j < cnt; j += 256) {
        int2 pr = pairs[p0 + j];
        int pos = atomicAdd(&lcur[pr.y - nbase], 1);
        col[pos] = pr.x;
    }
}

// ---------------- bf16 prep ----------------
__global__ __launch_bounds__(256) void prep_x_kernel(const float* __restrict__ x,
                                                     short* __restrict__ xb) {
    int i = (blockIdx.x * 256 + threadIdx.x) * 4;
    float4 v = *(const float4*)&x[i];
    short4 o;
    o.x = (short)f2bf(v.x); o.y = (short)f2bf(v.y);
    o.z = (short)f2bf(v.z); o.w = (short)f2bf(v.w);
    *(short4*)&xb[i] = o;
}

__global__ __launch_bounds__(256) void prep_w_kernel(
        const float* __restrict__ W1_l, const float* __restrict__ W1_r,
        const float* __restrict__ W2_l, const float* __restrict__ W2_r,
        short* __restrict__ W1t, short* __restrict__ W2lt, short* __restrict__ W2rt) {
    int i = blockIdx.x * 256 + threadIdx.x;
    if (i < 32768) {
        int n = i >> 8, k = i & 255;
        float v = (k < 128) ? W1_l[k * 128 + n] : W1_r[(k - 128) * 128 + n];
        W1t[i] = (short)f2bf(v);
    } else if (i < 40960) {
        int j = i - 32768, n = j >> 7, k = j & 127;
        W2lt[j] = (short)f2bf(W2_l[k * 64 + n]);
    } else {
        int j = i - 40960, n = j >> 7, k = j & 127;
        W2rt[j] = (short)f2bf(W2_r[k * 64 + n]);
    }
}

// ---------------- gather aggregation (bf16 in, fp32 accum) ----------------
__global__ __launch_bounds__(256) void agg128_kernel(
        const int* __restrict__ cursor, const int* __restrict__ deg_i,
        const int* __restrict__ col, const short* __restrict__ xb,
        const float* __restrict__ inv_deg, short* __restrict__ agg) {
    int node = blockIdx.x * 16 + (threadIdx.x >> 4);
    int lane = threadIdx.x & 15;
    int cnt = deg_i[node];
    int start = cursor[node];
    float acc[8] = {0.f};
    int s = (cnt > 0) ? col[start] : 0;
    for (int k = 0; k < cnt; k++) {
        int snext = (k + 1 < cnt) ? col[start + k + 1] : 0;
        short8 v = *(const short8*)(xb + (size_t)s * 128 + lane * 8);
        #pragma unroll
        for (int j = 0; j < 8; j++) acc[j] += bf2f(v[j]);
        s = snext;
    }
    float sc = inv_deg[node];
    short8 o;
    #pragma unroll
    for (int j = 0; j < 8; j++) o[j] = (short)f2bf(acc[j] * sc);
    *(short8*)(agg + (size_t)node * 128 + lane * 8) = o;
}

__global__ __launch_bounds__(256) void agg64_kernel(
        const int* __restrict__ cursor, const int* __restrict__ deg_i,
        const int* __restrict__ col, const short* __restrict__ pb,
        const float* __restrict__ inv_deg, float* __restrict__ agg) {
    int node = blockIdx.x * 32 + (threadIdx.x >> 3);
    int lane = threadIdx.x & 7;
    int cnt = deg_i[node];
    int start = cursor[node];
    float acc[8] = {0.f};
    int s = (cnt > 0) ? col[start] : 0;
    for (int k = 0; k < cnt; k++) {
        int snext = (k + 1 < cnt) ? col[start + k + 1] : 0;
        short8 v = *(const short8*)(pb + (size_t)s * 64 + lane * 8);
        #pragma unroll
        for (int j = 0; j < 8; j++) acc[j] += bf2f(v[j]);
        s = snext;
    }
    float sc = inv_deg[node];
    float* dst = agg + (size_t)node * 64 + lane * 8;
    float4 o0 = {acc[0] * sc, acc[1] * sc, acc[2] * sc, acc[3] * sc};
    float4 o1 = {acc[4] * sc, acc[5] * sc, acc[6] * sc, acc[7] * sc};
    *(float4*)dst = o0;
    *(float4*)(dst + 4) = o1;
}

// ---------------- persistent MFMA GEMMs (B cached in registers) ----------------
// h = relu([agg1|x] @ W1^T + b1), K=256, N=128.
// 2048 waves; each wave owns one 64-col half and ~6 row-tiles of 16.
// B-slice (64 cols x 256 K) lives in 32 short8 registers for the wave's lifetime.
__global__ __launch_bounds__(256, 2) void gemm1_mfma(
        const short* __restrict__ agg1, const short* __restrict__ xb,
        const short* __restrict__ W1t, const float* __restrict__ b1,
        short* __restrict__ h) {
    const int wave = threadIdx.x >> 6, lane = threadIdx.x & 63;
    const int m = lane & 15, q = lane >> 4;
    const int wid = blockIdx.x * 4 + wave;      // 0..2047
    const int half = wid & 1;
    short8 breg[4][8];
    #pragma unroll
    for (int t = 0; t < 4; t++)
        #pragma unroll
        for (int c = 0; c < 8; c++)
            breg[t][c] = *(const short8*)(W1t + (size_t)(half * 64 + t * 16 + m) * 256 + c * 32 + q * 8);
    float bias[4];
    #pragma unroll
    for (int t = 0; t < 4; t++) bias[t] = b1[half * 64 + t * 16 + m];

    for (int tile = wid >> 1; tile < 6250; tile += 1024) {
        const short* arow = agg1 + (size_t)(tile * 16 + m) * 128;
        const short* xrow = xb + (size_t)(tile * 16 + m) * 128;
        short8 a[8];
        #pragma unroll
        for (int c = 0; c < 4; c++) a[c] = *(const short8*)(arow + c * 32 + q * 8);
        #pragma unroll
        for (int c = 0; c < 4; c++) a[c + 4] = *(const short8*)(xrow + c * 32 + q * 8);
        f32x4 acc[4];
        #pragma unroll
        for (int t = 0; t < 4; t++) acc[t] = (f32x4){0.f, 0.f, 0.f, 0.f};
        #pragma unroll
        for (int c = 0; c < 8; c++)
            #pragma unroll
            for (int t = 0; t < 4; t++)
                acc[t] = __builtin_amdgcn_mfma_f32_16x16x32_bf16(a[c], breg[t][c], acc[t], 0, 0, 0);
        #pragma unroll
        for (int t = 0; t < 4; t++) {
            int colc = half * 64 + t * 16 + m;
            #pragma unroll
            for (int r = 0; r < 4; r++) {
                int rr = tile * 16 + q * 4 + r;
                h[(size_t)rr * 128 + colc] = (short)f2bf(fmaxf(acc[t][r] + bias[t], 0.f));
            }
        }
    }
}

// p = h @ W2_l (K=128, N=64), bf16 out. Persistent, B in 16 regs.
__global__ __launch_bounds__(256, 4) void proj_mfma(
        const short* __restrict__ h, const short* __restrict__ W2lt,
        short* __restrict__ p) {
    const int wave = threadIdx.x >> 6, lane = threadIdx.x & 63;
    const int m = lane & 15, q = lane >> 4;
    const int wid = blockIdx.x * 4 + wave;      // 0..2047
    short8 breg[4][4];
    #pragma unroll
    for (int t = 0; t < 4; t++)
        #pragma unroll
        for (int c = 0; c < 4; c++)
            breg[t][c] = *(const short8*)(W2lt + (size_t)(t * 16 + m) * 128 + c * 32 + q * 8);

    for (int tile = wid; tile < 6250; tile += 2048) {
        const short* hrow = h + (size_t)(tile * 16 + m) * 128;
        short8 a[4];
        #pragma unroll
        for (int c = 0; c < 4; c++) a[c] = *(const short8*)(hrow + c * 32 + q * 8);
        f32x4 acc[4];
        #pragma unroll
        for (int t = 0; t < 4; t++) acc[t] = (f32x4){0.f, 0.f, 0.f, 0.f};
        #pragma unroll
        for (int c = 0; c < 4; c++)
            #pragma unroll
            for (int t = 0; t < 4; t++)
                acc[t] = __builtin_amdgcn_mfma_f32_16x16x32_bf16(a[c], breg[t][c], acc[t], 0, 0, 0);
        #pragma unroll
        for (int t = 0; t < 4; t++) {
            int colc = t * 16 + m;
            #pragma unroll
            for (int r = 0; r < 4; r++) {
                int rr = tile * 16 + q * 4 + r;
                p[(size_t)rr * 64 + colc] = (short)f2bf(acc[t][r]);
            }
        }
    }
}

// out = agg2 + h @ W2_r + b2 (K=128, N=64), fp32 out. Persistent.
__global__ __launch_bounds__(256, 4) void gemm2_mfma(
        const short* __restrict__ h, const short* __restrict__ W2rt,
        const float* __restrict__ agg2, const float* __restrict__ b2,
        float* __restrict__ out) {
    const int wave = threadIdx.x >> 6, lane = threadIdx.x & 63;
    const int m = lane & 15, q = lane >> 4;
    const int wid = blockIdx.x * 4 + wave;
    short8 breg[4][4];
    #pragma unroll
    for (int t = 0; t < 4; t++)
        #pragma unroll
        for (int c = 0; c < 4; c++)
            breg[t][c] = *(const short8*)(W2rt + (size_t)(t * 16 + m) * 128 + c * 32 + q * 8);
    float bias[4];
    #pragma unroll
    for (int t = 0; t < 4; t++) bias[t] = b2[t * 16 + m];

    for (int tile = wid; tile < 6250; tile += 2048) {
        const short* hrow = h + (size_t)(tile * 16 + m) * 128;
        short8 a[4];
        #pragma unroll
        for (int c = 0; c < 4; c++) a[c] = *(const short8*)(hrow + c * 32 + q * 8);
        f32x4 acc[4];
        #pragma unroll
        for (int t = 0; t < 4; t++) acc[t] = (f32x4){0.f, 0.f, 0.f, 0.f};
        #pragma unroll
        for (int c = 0; c < 4; c++)
            #pragma unroll
            for (int t = 0; t < 4; t++)
                acc[t] = __builtin_amdgcn_mfma_f32_16x16x32_bf16(a[c], breg[t][c], acc[t], 0, 0, 0);
        #pragma unroll
        for (int t = 0; t < 4; t++) {
            int colc = t * 16 + m;
            #pragma unroll
            for (int r = 0; r < 4; r++) {
                int rr = tile * 16 + q * 4 + r;
                out[(size_t)rr * 64 + colc] = acc[t][r] + bias[t] + agg2[(size_t)rr * 64 + colc];
            }
        }
    }
}

extern "C" void kernel_launch(void* const* d_in, const int* in_sizes, int n_in,
                              void* d_out, int out_size, void* d_ws, size_t ws_size,
                              hipStream_t stream) {
    const float* x    = (const float*)d_in[0];
    const int*   edge = (const int*)d_in[1];
    const float* W1_l = (const float*)d_in[2];
    const float* b1   = (const float*)d_in[3];
    const float* W1_r = (const float*)d_in[4];
    const float* W2_l = (const float*)d_in[5];
    const float* b2   = (const float*)d_in[6];
    const float* W2_r = (const float*)d_in[7];
    float* out = (float*)d_out;

    // ---- workspace layout (~97.7 MB) ----
    int* iw = (int*)d_ws;
    int* deg_i  = iw;                    // 100000
    int* cursor = iw + 100000;           // 100000 (row starts)
    int* pre    = iw + 200000;           // 100352
    int* blk    = iw + 300352;           // 128
    int* col    = iw + 300480;           // 1600000
    int* bcnt   = iw + 1900480;          // 256
    int* bstart = iw + 1900736;          // 256
    int* bcur   = iw + 1900992;          // 256
    int* flag   = iw + 1901248;          // pad to 1901312
    float* inv_deg = (float*)iw + 1901312;   // 100096
    int2*  pairs   = (int2*)(iw + 2001408); // 1.6M int2 (12.8 MB)
    short* xb   = (short*)(iw + 5201408);    // 12.8M bf16
    short* hb   = xb + 12800000;             // 12.8M bf16
    short* ag1  = hb + 12800000;             // 12.8M bf16
    short* W1t  = ag1 + 12800000;            // 32768
    short* W2lt = W1t + 32768;               // 8192
    short* W2rt = W2lt + 8192;               // 8192
    short* pb   = ag1;                       // overlay: agg1 dead after gemm1
    float* agg2 = (float*)xb;                // overlay: xb dead after gemm1

    detect_kernel<<<1, 256, 0, stream>>>(edge, flag);
    hipMemsetAsync(bcnt, 0, NB * sizeof(int), stream);

    // bucketed CSR build
    bucket_count_kernel<<<391, 256, 0, stream>>>(edge, flag, bcnt);
    bucket_scan_kernel<<<1, 256, 0, stream>>>(bcnt, bstart, bcur);
    binscat_kernel<<<391, 256, 0, stream>>>(edge, flag, bcur, pairs);
    bucket_deg_kernel<<<NB, 256, 0, stream>>>(bstart, bcnt, pairs, deg_i);
    scan1_kernel<<<98, 256, 0, stream>>>(deg_i, pre, blk);
    scan2_kernel<<<1, 128, 0, stream>>>(blk);
    scan3_kernel<<<98, 256, 0, stream>>>(pre, blk, deg_i, cursor, inv_deg);
    bucket_fill_kernel<<<NB, 256, 0, stream>>>(bstart, bcnt, pairs, cursor, col);

    prep_x_kernel<<<12500, 256, 0, stream>>>(x, xb);
    prep_w_kernel<<<192, 256, 0, stream>>>(W1_l, W1_r, W2_l, W2_r, W1t, W2lt, W2rt);

    // layer 1
    agg128_kernel<<<6250, 256, 0, stream>>>(cursor, deg_i, col, xb, inv_deg, ag1);
    gemm1_mfma<<<512, 256, 0, stream>>>(ag1, xb, W1t, b1, hb);

    // layer 2
    proj_mfma<<<512, 256, 0, stream>>>(hb, W2lt, pb);
    agg64_kernel<<<3125, 256, 0, stream>>>(cursor, deg_i, col, pb, inv_deg, agg2);
    gemm2_mfma<<<512, 256, 0, stream>>>(hb, W2rt, agg2, b2, out);
}

// Round 6
// 328.885 us; speedup vs baseline: 5.3036x; 1.0552x over previous
//
#include <hip/hip_runtime.h>

#define N_NODES   100000
#define N_EDGES   1600000
#define BSHIFT    9
#define NB        196        // ceil(100000 / 512)

typedef __attribute__((ext_vector_type(8))) short short8;
typedef __attribute__((ext_vector_type(4))) float f32x4;

__device__ __forceinline__ unsigned short f2bf(float f) {
    unsigned u = __float_as_uint(f);
    u += 0x7FFF + ((u >> 16) & 1);          // round-to-nearest-even
    return (unsigned short)(u >> 16);
}
__device__ __forceinline__ float bf2f(short s) {
    return __uint_as_float(((unsigned)(unsigned short)s) << 16);
}

// ---------------- edge-index width detector ----------------
__global__ void detect_kernel(const int* __restrict__ e32, int* __restrict__ flag) {
    __shared__ int nz;
    if (threadIdx.x == 0) nz = 0;
    __syncthreads();
    int v = 0;
    for (int i = threadIdx.x; i < 1024; i += 256) v |= e32[2 * i + 1];
    if (v) atomicOr(&nz, 1);
    __syncthreads();
    if (threadIdx.x == 0) *flag = (nz == 0) ? 1 : 0;
}

__device__ __forceinline__ int load_src(const int* e, int is64, int i) {
    return is64 ? e[2 * i] : e[i];
}
__device__ __forceinline__ int load_dst(const int* e, int is64, int i) {
    return is64 ? e[2 * (N_EDGES + i)] : e[N_EDGES + i];
}

// ---------------- bucketed CSR build ----------------
__global__ __launch_bounds__(256) void bucket_count_kernel(
        const int* __restrict__ e, const int* __restrict__ flag,
        int* __restrict__ bcnt) {
    __shared__ int s_cnt[NB];
    for (int t = threadIdx.x; t < NB; t += 256) s_cnt[t] = 0;
    __syncthreads();
    int is64 = *flag;
    int i0 = blockIdx.x * 4096;
    int n = min(4096, N_EDGES - i0);
    for (int t = 0; t < 16; t++) {
        int k = t * 256 + threadIdx.x;
        if (k < n) {
            int d = load_dst(e, is64, i0 + k);
            atomicAdd(&s_cnt[d >> BSHIFT], 1);
        }
    }
    __syncthreads();
    for (int t = threadIdx.x; t < NB; t += 256)
        if (s_cnt[t]) atomicAdd(&bcnt[t], s_cnt[t]);
}

__global__ __launch_bounds__(256) void bucket_scan_kernel(
        const int* __restrict__ bcnt, int* __restrict__ bstart, int* __restrict__ bcur) {
    __shared__ int s[256];
    int v = (threadIdx.x < NB) ? bcnt[threadIdx.x] : 0;
    s[threadIdx.x] = v;
    __syncthreads();
    for (int off = 1; off < 256; off <<= 1) {
        int t = (threadIdx.x >= off) ? s[threadIdx.x - off] : 0;
        __syncthreads();
        s[threadIdx.x] += t;
        __syncthreads();
    }
    if (threadIdx.x < NB) {
        int st = s[threadIdx.x] - v;
        bstart[threadIdx.x] = st;
        bcur[threadIdx.x] = st;
    }
}

__global__ __launch_bounds__(256) void binscat_kernel(
        const int* __restrict__ e, const int* __restrict__ flag,
        int* __restrict__ bcur, int2* __restrict__ pairs) {
    __shared__ int2 s_pairs[4096];
    __shared__ int s_cnt[256], s_off[256], s_base[256], s_cur[256];
    const int tid = threadIdx.x;
    s_cnt[tid] = 0;
    __syncthreads();
    int is64 = *flag;
    int i0 = blockIdx.x * 4096;
    int n = min(4096, N_EDGES - i0);
    for (int t = 0; t < 16; t++) {
        int k = t * 256 + tid;
        if (k < n) {
            int d = load_dst(e, is64, i0 + k);
            atomicAdd(&s_cnt[d >> BSHIFT], 1);
        }
    }
    __syncthreads();
    int v = s_cnt[tid];
    s_off[tid] = v;
    __syncthreads();
    for (int off = 1; off < 256; off <<= 1) {
        int t = (tid >= off) ? s_off[tid - off] : 0;
        __syncthreads();
        s_off[tid] += t;
        __syncthreads();
    }
    int excl = s_off[tid] - v;
    int gb = 0;
    if (tid < NB && v > 0) gb = atomicAdd(&bcur[tid], v);
    s_off[tid] = excl;
    s_base[tid] = gb;
    s_cur[tid] = excl;
    __syncthreads();
    for (int t = 0; t < 16; t++) {
        int k = t * 256 + tid;
        if (k < n) {
            int s = load_src(e, is64, i0 + k);
            int d = load_dst(e, is64, i0 + k);
            int pos = atomicAdd(&s_cur[d >> BSHIFT], 1);
            s_pairs[pos] = (int2){s, d};
        }
    }
    __syncthreads();
    for (int j = tid; j < n; j += 256) {
        int2 pr = s_pairs[j];
        int b = pr.y >> BSHIFT;
        pairs[s_base[b] + (j - s_off[b])] = pr;
    }
}

__global__ __launch_bounds__(256) void bucket_deg_kernel(
        const int* __restrict__ bstart, const int* __restrict__ bcnt,
        const int2* __restrict__ pairs, int* __restrict__ deg_i) {
    __shared__ int ldeg[512];
    int b = blockIdx.x;
    for (int t = threadIdx.x; t < 512; t += 256) ldeg[t] = 0;
    __syncthreads();
    int p0 = bstart[b], cnt = bcnt[b];
    int nbase = b << BSHIFT;
    for (int j = threadIdx.x; j < cnt; j += 256) {
        int d = pairs[p0 + j].y;
        atomicAdd(&ldeg[d - nbase], 1);
    }
    __syncthreads();
    for (int t = threadIdx.x; t < 512; t += 256) {
        int idx = nbase + t;
        if (idx < N_NODES) deg_i[idx] = ldeg[t];
    }
}

__global__ __launch_bounds__(256) void scan1_kernel(const int* __restrict__ deg_i,
                                                    int* __restrict__ pre,
                                                    int* __restrict__ blk) {
    __shared__ int s[256];
    int base = blockIdx.x * 1024 + threadIdx.x * 4;
    int v0 = 0, v1 = 0, v2 = 0, v3 = 0;
    if (base + 3 < N_NODES) {
        int4 q = *(const int4*)&deg_i[base];
        v0 = q.x; v1 = q.y; v2 = q.z; v3 = q.w;
    } else {
        if (base + 0 < N_NODES) v0 = deg_i[base + 0];
        if (base + 1 < N_NODES) v1 = deg_i[base + 1];
        if (base + 2 < N_NODES) v2 = deg_i[base + 2];
        if (base + 3 < N_NODES) v3 = deg_i[base + 3];
    }
    int tsum = v0 + v1 + v2 + v3;
    s[threadIdx.x] = tsum;
    __syncthreads();
    for (int off = 1; off < 256; off <<= 1) {
        int t = (threadIdx.x >= off) ? s[threadIdx.x - off] : 0;
        __syncthreads();
        s[threadIdx.x] += t;
        __syncthreads();
    }
    int excl = s[threadIdx.x] - tsum;
    pre[base + 0] = excl;
    pre[base + 1] = excl + v0;
    pre[base + 2] = excl + v0 + v1;
    pre[base + 3] = excl + v0 + v1 + v2;
    if (threadIdx.x == 255) blk[blockIdx.x] = s[255];
}

__global__ __launch_bounds__(128) void scan2_kernel(int* __restrict__ blk) {
    __shared__ int s[128];
    int v = (threadIdx.x < 98) ? blk[threadIdx.x] : 0;
    s[threadIdx.x] = v;
    __syncthreads();
    for (int off = 1; off < 128; off <<= 1) {
        int t = (threadIdx.x >= off) ? s[threadIdx.x - off] : 0;
        __syncthreads();
        s[threadIdx.x] += t;
        __syncthreads();
    }
    if (threadIdx.x < 98) blk[threadIdx.x] = s[threadIdx.x] - v;
}

__global__ __launch_bounds__(256) void scan3_kernel(const int* __restrict__ pre,
                                                    const int* __restrict__ blk,
                                                    const int* __restrict__ deg_i,
                                                    int* __restrict__ cursor,
                                                    float* __restrict__ inv_deg) {
    int off = blk[blockIdx.x];
    int base = blockIdx.x * 1024 + threadIdx.x * 4;
    #pragma unroll
    for (int j = 0; j < 4; j++) {
        int idx = base + j;
        if (idx < N_NODES) {
            cursor[idx] = pre[idx] + off;        // row START (immutable)
            inv_deg[idx] = 1.0f / fmaxf((float)deg_i[idx], 1.0f);
        }
    }
}

__global__ __launch_bounds__(256) void bucket_fill_kernel(
        const int* __restrict__ bstart, const int* __restrict__ bcnt,
        const int2* __restrict__ pairs, const int* __restrict__ cursor,
        int* __restrict__ col) {
    __shared__ int lcur[512];
    int b = blockIdx.x;
    int nbase = b << BSHIFT;
    for (int t = threadIdx.x; t < 512; t += 256) {
        int idx = nbase + t;
        lcur[t] = (idx < N_NODES) ? cursor[idx] : 0;
    }
    __syncthreads();
    int p0 = bstart[b], cnt = bcnt[b];
    for (int j = threadIdx.x; j < cnt; j += 256) {
        int2 pr = pairs[p0 + j];
        int pos = atomicAdd(&lcur[pr.y - nbase], 1);
        col[pos] = pr.x;
    }
}

// ---------------- bf16 prep ----------------
__global__ __launch_bounds__(256) void prep_x_kernel(const float* __restrict__ x,
                                                     short* __restrict__ xb) {
    int i = (blockIdx.x * 256 + threadIdx.x) * 4;
    float4 v = *(const float4*)&x[i];
    short4 o;
    o.x = (short)f2bf(v.x); o.y = (short)f2bf(v.y);
    o.z = (short)f2bf(v.z); o.w = (short)f2bf(v.w);
    *(short4*)&xb[i] = o;
}

__global__ __launch_bounds__(256) void prep_w_kernel(
        const float* __restrict__ W1_l, const float* __restrict__ W1_r,
        const float* __restrict__ W2_l, const float* __restrict__ W2_r,
        short* __restrict__ W1t, short* __restrict__ W2lt, short* __restrict__ W2rt) {
    int i = blockIdx.x * 256 + threadIdx.x;
    if (i < 32768) {
        int n = i >> 8, k = i & 255;
        float v = (k < 128) ? W1_l[k * 128 + n] : W1_r[(k - 128) * 128 + n];
        W1t[i] = (short)f2bf(v);
    } else if (i < 40960) {
        int j = i - 32768, n = j >> 7, k = j & 127;
        W2lt[j] = (short)f2bf(W2_l[k * 64 + n]);
    } else {
        int j = i - 40960, n = j >> 7, k = j & 127;
        W2rt[j] = (short)f2bf(W2_r[k * 64 + n]);
    }
}

// ---------------- gather aggregation (4-deep MLP unroll) ----------------
__global__ __launch_bounds__(256) void agg128_kernel(
        const int* __restrict__ cursor, const int* __restrict__ deg_i,
        const int* __restrict__ col, const short* __restrict__ xb,
        const float* __restrict__ inv_deg, short* __restrict__ agg) {
    int node = blockIdx.x * 16 + (threadIdx.x >> 4);
    int lane = threadIdx.x & 15;
    int cnt = deg_i[node];
    int start = cursor[node];
    float acc[8] = {0.f};
    int k = 0;
    for (; k + 4 <= cnt; k += 4) {
        int s0 = col[start + k + 0];
        int s1 = col[start + k + 1];
        int s2 = col[start + k + 2];
        int s3 = col[start + k + 3];
        short8 v0 = *(const short8*)(xb + (size_t)s0 * 128 + lane * 8);
        short8 v1 = *(const short8*)(xb + (size_t)s1 * 128 + lane * 8);
        short8 v2 = *(const short8*)(xb + (size_t)s2 * 128 + lane * 8);
        short8 v3 = *(const short8*)(xb + (size_t)s3 * 128 + lane * 8);
        #pragma unroll
        for (int j = 0; j < 8; j++)
            acc[j] += (bf2f(v0[j]) + bf2f(v1[j])) + (bf2f(v2[j]) + bf2f(v3[j]));
    }
    for (; k < cnt; k++) {
        int s = col[start + k];
        short8 v = *(const short8*)(xb + (size_t)s * 128 + lane * 8);
        #pragma unroll
        for (int j = 0; j < 8; j++) acc[j] += bf2f(v[j]);
    }
    float sc = inv_deg[node];
    short8 o;
    #pragma unroll
    for (int j = 0; j < 8; j++) o[j] = (short)f2bf(acc[j] * sc);
    *(short8*)(agg + (size_t)node * 128 + lane * 8) = o;
}

__global__ __launch_bounds__(256) void agg64_kernel(
        const int* __restrict__ cursor, const int* __restrict__ deg_i,
        const int* __restrict__ col, const short* __restrict__ pb,
        const float* __restrict__ inv_deg, float* __restrict__ agg) {
    int node = blockIdx.x * 32 + (threadIdx.x >> 3);
    int lane = threadIdx.x & 7;
    int cnt = deg_i[node];
    int start = cursor[node];
    float acc[8] = {0.f};
    int k = 0;
    for (; k + 4 <= cnt; k += 4) {
        int s0 = col[start + k + 0];
        int s1 = col[start + k + 1];
        int s2 = col[start + k + 2];
        int s3 = col[start + k + 3];
        short8 v0 = *(const short8*)(pb + (size_t)s0 * 64 + lane * 8);
        short8 v1 = *(const short8*)(pb + (size_t)s1 * 64 + lane * 8);
        short8 v2 = *(const short8*)(pb + (size_t)s2 * 64 + lane * 8);
        short8 v3 = *(const short8*)(pb + (size_t)s3 * 64 + lane * 8);
        #pragma unroll
        for (int j = 0; j < 8; j++)
            acc[j] += (bf2f(v0[j]) + bf2f(v1[j])) + (bf2f(v2[j]) + bf2f(v3[j]));
    }
    for (; k < cnt; k++) {
        int s = col[start + k];
        short8 v = *(const short8*)(pb + (size_t)s * 64 + lane * 8);
        #pragma unroll
        for (int j = 0; j < 8; j++) acc[j] += bf2f(v[j]);
    }
    float sc = inv_deg[node];
    float* dst = agg + (size_t)node * 64 + lane * 8;
    float4 o0 = {acc[0] * sc, acc[1] * sc, acc[2] * sc, acc[3] * sc};
    float4 o1 = {acc[4] * sc, acc[5] * sc, acc[6] * sc, acc[7] * sc};
    *(float4*)dst = o0;
    *(float4*)(dst + 4) = o1;
}

// ---------------- persistent MFMA GEMMs (B cached in registers) ----------------
__global__ __launch_bounds__(256, 2) void gemm1_mfma(
        const short* __restrict__ agg1, const short* __restrict__ xb,
        const short* __restrict__ W1t, const float* __restrict__ b1,
        short* __restrict__ h) {
    const int wave = threadIdx.x >> 6, lane = threadIdx.x & 63;
    const int m = lane & 15, q = lane >> 4;
    const int wid = blockIdx.x * 4 + wave;      // 0..2047
    const int half = wid & 1;
    short8 breg[4][8];
    #pragma unroll
    for (int t = 0; t < 4; t++)
        #pragma unroll
        for (int c = 0; c < 8; c++)
            breg[t][c] = *(const short8*)(W1t + (size_t)(half * 64 + t * 16 + m) * 256 + c * 32 + q * 8);
    float bias[4];
    #pragma unroll
    for (int t = 0; t < 4; t++) bias[t] = b1[half * 64 + t * 16 + m];

    for (int tile = wid >> 1; tile < 6250; tile += 1024) {
        const short* arow = agg1 + (size_t)(tile * 16 + m) * 128;
        const short* xrow = xb + (size_t)(tile * 16 + m) * 128;
        short8 a[8];
        #pragma unroll
        for (int c = 0; c < 4; c++) a[c] = *(const short8*)(arow + c * 32 + q * 8);
        #pragma unroll
        for (int c = 0; c < 4; c++) a[c + 4] = *(const short8*)(xrow + c * 32 + q * 8);
        f32x4 acc[4];
        #pragma unroll
        for (int t = 0; t < 4; t++) acc[t] = (f32x4){0.f, 0.f, 0.f, 0.f};
        #pragma unroll
        for (int c = 0; c < 8; c++)
            #pragma unroll
            for (int t = 0; t < 4; t++)
                acc[t] = __builtin_amdgcn_mfma_f32_16x16x32_bf16(a[c], breg[t][c], acc[t], 0, 0, 0);
        #pragma unroll
        for (int t = 0; t < 4; t++) {
            int colc = half * 64 + t * 16 + m;
            #pragma unroll
            for (int r = 0; r < 4; r++) {
                int rr = tile * 16 + q * 4 + r;
                h[(size_t)rr * 128 + colc] = (short)f2bf(fmaxf(acc[t][r] + bias[t], 0.f));
            }
        }
    }
}

__global__ __launch_bounds__(256, 4) void proj_mfma(
        const short* __restrict__ h, const short* __restrict__ W2lt,
        short* __restrict__ p) {
    const int wave = threadIdx.x >> 6, lane = threadIdx.x & 63;
    const int m = lane & 15, q = lane >> 4;
    const int wid = blockIdx.x * 4 + wave;      // 0..2047
    short8 breg[4][4];
    #pragma unroll
    for (int t = 0; t < 4; t++)
        #pragma unroll
        for (int c = 0; c < 4; c++)
            breg[t][c] = *(const short8*)(W2lt + (size_t)(t * 16 + m) * 128 + c * 32 + q * 8);

    for (int tile = wid; tile < 6250; tile += 2048) {
        const short* hrow = h + (size_t)(tile * 16 + m) * 128;
        short8 a[4];
        #pragma unroll
        for (int c = 0; c < 4; c++) a[c] = *(const short8*)(hrow + c * 32 + q * 8);
        f32x4 acc[4];
        #pragma unroll
        for (int t = 0; t < 4; t++) acc[t] = (f32x4){0.f, 0.f, 0.f, 0.f};
        #pragma unroll
        for (int c = 0; c < 4; c++)
            #pragma unroll
            for (int t = 0; t < 4; t++)
                acc[t] = __builtin_amdgcn_mfma_f32_16x16x32_bf16(a[c], breg[t][c], acc[t], 0, 0, 0);
        #pragma unroll
        for (int t = 0; t < 4; t++) {
            int colc = t * 16 + m;
            #pragma unroll
            for (int r = 0; r < 4; r++) {
                int rr = tile * 16 + q * 4 + r;
                p[(size_t)rr * 64 + colc] = (short)f2bf(acc[t][r]);
            }
        }
    }
}

__global__ __launch_bounds__(256, 4) void gemm2_mfma(
        const short* __restrict__ h, const short* __restrict__ W2rt,
        const float* __restrict__ agg2, const float* __restrict__ b2,
        float* __restrict__ out) {
    const int wave = threadIdx.x >> 6, lane = threadIdx.x & 63;
    const int m = lane & 15, q = lane >> 4;
    const int wid = blockIdx.x * 4 + wave;
    short8 breg[4][4];
    #pragma unroll
    for (int t = 0; t < 4; t++)
        #pragma unroll
        for (int c = 0; c < 4; c++)
            breg[t][c] = *(const short8*)(W2rt + (size_t)(t * 16 + m) * 128 + c * 32 + q * 8);
    float bias[4];
    #pragma unroll
    for (int t = 0; t < 4; t++) bias[t] = b2[t * 16 + m];

    for (int tile = wid; tile < 6250; tile += 2048) {
        const short* hrow = h + (size_t)(tile * 16 + m) * 128;
        short8 a[4];
        #pragma unroll
        for (int c = 0; c < 4; c++) a[c] = *(const short8*)(hrow + c * 32 + q * 8);
        f32x4 acc[4];
        #pragma unroll
        for (int t = 0; t < 4; t++) acc[t] = (f32x4){0.f, 0.f, 0.f, 0.f};
        #pragma unroll
        for (int c = 0; c < 4; c++)
            #pragma unroll
            for (int t = 0; t < 4; t++)
                acc[t] = __builtin_amdgcn_mfma_f32_16x16x32_bf16(a[c], breg[t][c], acc[t], 0, 0, 0);
        #pragma unroll
        for (int t = 0; t < 4; t++) {
            int colc = t * 16 + m;
            #pragma unroll
            for (int r = 0; r < 4; r++) {
                int rr = tile * 16 + q * 4 + r;
                out[(size_t)rr * 64 + colc] = acc[t][r] + bias[t] + agg2[(size_t)rr * 64 + colc];
            }
        }
    }
}

extern "C" void kernel_launch(void* const* d_in, const int* in_sizes, int n_in,
                              void* d_out, int out_size, void* d_ws, size_t ws_size,
                              hipStream_t stream) {
    const float* x    = (const float*)d_in[0];
    const int*   edge = (const int*)d_in[1];
    const float* W1_l = (const float*)d_in[2];
    const float* b1   = (const float*)d_in[3];
    const float* W1_r = (const float*)d_in[4];
    const float* W2_l = (const float*)d_in[5];
    const float* b2   = (const float*)d_in[6];
    const float* W2_r = (const float*)d_in[7];
    float* out = (float*)d_out;

    // ---- workspace layout (~97.7 MB) ----
    int* iw = (int*)d_ws;
    int* deg_i  = iw;                    // 100000
    int* cursor = iw + 100000;           // 100000 (row starts)
    int* pre    = iw + 200000;           // 100352
    int* blk    = iw + 300352;           // 128
    int* col    = iw + 300480;           // 1600000
    int* bcnt   = iw + 1900480;          // 256
    int* bstart = iw + 1900736;          // 256
    int* bcur   = iw + 1900992;          // 256
    int* flag   = iw + 1901248;          // pad to 1901312
    float* inv_deg = (float*)iw + 1901312;   // 100096
    int2*  pairs   = (int2*)(iw + 2001408); // 1.6M int2 (12.8 MB)
    short* xb   = (short*)(iw + 5201408);    // 12.8M bf16
    short* hb   = xb + 12800000;             // 12.8M bf16
    short* ag1  = hb + 12800000;             // 12.8M bf16
    short* W1t  = ag1 + 12800000;            // 32768
    short* W2lt = W1t + 32768;               // 8192
    short* W2rt = W2lt + 8192;               // 8192
    short* pb   = ag1;                       // overlay: agg1 dead after gemm1
    float* agg2 = (float*)xb;                // overlay: xb dead after gemm1

    detect_kernel<<<1, 256, 0, stream>>>(edge, flag);
    hipMemsetAsync(bcnt, 0, NB * sizeof(int), stream);

    // bucketed CSR build
    bucket_count_kernel<<<391, 256, 0, stream>>>(edge, flag, bcnt);
    bucket_scan_kernel<<<1, 256, 0, stream>>>(bcnt, bstart, bcur);
    binscat_kernel<<<391, 256, 0, stream>>>(edge, flag, bcur, pairs);
    bucket_deg_kernel<<<NB, 256, 0, stream>>>(bstart, bcnt, pairs, deg_i);
    scan1_kernel<<<98, 256, 0, stream>>>(deg_i, pre, blk);
    scan2_kernel<<<1, 128, 0, stream>>>(blk);
    scan3_kernel<<<98, 256, 0, stream>>>(pre, blk, deg_i, cursor, inv_deg);
    bucket_fill_kernel<<<NB, 256, 0, stream>>>(bstart, bcnt, pairs, cursor, col);

    prep_x_kernel<<<12500, 256, 0, stream>>>(x, xb);
    prep_w_kernel<<<192, 256, 0, stream>>>(W1_l, W1_r, W2_l, W2_r, W1t, W2lt, W2rt);

    // layer 1
    agg128_kernel<<<6250, 256, 0, stream>>>(cursor, deg_i, col, xb, inv_deg, ag1);
    gemm1_mfma<<<512, 256, 0, stream>>>(ag1, xb, W1t, b1, hb);

    // layer 2
    proj_mfma<<<512, 256, 0, stream>>>(hb, W2lt, pb);
    agg64_kernel<<<3125, 256, 0, stream>>>(cursor, deg_i, col, pb, inv_deg, agg2);
    gemm2_mfma<<<512, 256, 0, stream>>>(hb, W2rt, agg2, b2, out);
}